// Round 4
// baseline (1041.565 us; speedup 1.0000x reference)
//
#include <hip/hip_runtime.h>

#define D_IN 50
#define LN_EPS 1e-5f
#define BSH 6  // 64 nodes per bucket

typedef __bf16 bf16_t;
typedef bf16_t bf16x8 __attribute__((ext_vector_type(8)));
typedef bf16_t bf16x4 __attribute__((ext_vector_type(4)));
typedef bf16_t bf16x2 __attribute__((ext_vector_type(2)));
typedef float f32x4_t __attribute__((ext_vector_type(4)));

// ---------------------------------------------------------------- CSR build
// bucket histogram: ~1563 hot counters (vs 100k lines before)
__global__ void hist_b_k(const int* __restrict__ dst, int* __restrict__ bcnt, int e) {
    int i = blockIdx.x * blockDim.x + threadIdx.x;
    if (i < e) atomicAdd(&bcnt[dst[i] >> BSH], 1);
}

__global__ void scan_partial_k(const int* __restrict__ cnt, int* __restrict__ part, int n) {
    __shared__ int lds[256];
    int base = blockIdx.x * 1024;
    int t = threadIdx.x;
    int s = 0;
    for (int j = 0; j < 4; j++) {
        int idx = base + t * 4 + j;
        if (idx < n) s += cnt[idx];
    }
    lds[t] = s;
    __syncthreads();
    for (int off = 128; off > 0; off >>= 1) {
        if (t < off) lds[t] += lds[t + off];
        __syncthreads();
    }
    if (t == 0) part[blockIdx.x] = lds[0];
}

__global__ void scan_root_k(int* part, int nb) {
    if (threadIdx.x == 0 && blockIdx.x == 0) {
        int run = 0;
        for (int i = 0; i < nb; i++) { int v = part[i]; part[i] = run; run += v; }
    }
}

__global__ void scan_final_k(const int* __restrict__ cnt, const int* __restrict__ part,
                             int* __restrict__ row_ptr, int* __restrict__ pos, int n) {
    __shared__ int lds[256];
    int base = blockIdx.x * 1024;
    int t = threadIdx.x;
    int v[4];
    int s = 0;
    for (int j = 0; j < 4; j++) {
        int idx = base + t * 4 + j;
        v[j] = (idx < n) ? cnt[idx] : 0;
        s += v[j];
    }
    lds[t] = s;
    __syncthreads();
    for (int off = 1; off < 256; off <<= 1) {
        int xv = (t >= off) ? lds[t - off] : 0;
        __syncthreads();
        lds[t] += xv;
        __syncthreads();
    }
    int ex = (t > 0 ? lds[t - 1] : 0) + part[blockIdx.x];
    for (int j = 0; j < 4; j++) {
        int idx = base + t * 4 + j;
        if (idx < n) {
            row_ptr[idx] = ex;
            pos[idx] = ex;
            if (idx == n - 1) row_ptr[n] = ex + v[j];
            ex += v[j];
        }
    }
}

// scatter (src,dst) pairs into bucket regions (8B appends at bucket tails)
__global__ void bfill_k(const int* __restrict__ src, const int* __restrict__ dst,
                        int* __restrict__ bpos, int2* __restrict__ pairs, int e) {
    int i = blockIdx.x * blockDim.x + threadIdx.x;
    if (i < e) {
        int d = dst[i];
        int p = atomicAdd(&bpos[d >> BSH], 1);
        pairs[p] = make_int2(src[i], d);
    }
}

// per-bucket node histogram in LDS, coalesced cnt writes
__global__ void nhist_k(const int2* __restrict__ pairs, const int* __restrict__ boff,
                        int* __restrict__ cnt, int n) {
    __shared__ int lc[64];
    int b = blockIdx.x;
    int t = threadIdx.x;
    if (t < 64) lc[t] = 0;
    __syncthreads();
    int s = boff[b], e = boff[b + 1];
    for (int i = s + t; i < e; i += 256) {
        atomicAdd(&lc[pairs[i].y & 63], 1);
    }
    __syncthreads();
    int nd = (b << BSH) + t;
    if (t < 64 && nd < n) cnt[nd] = lc[t];
}

// per-bucket col fill: LDS position counters, col writes within ~4KB span
__global__ void cfill_k(const int2* __restrict__ pairs, const int* __restrict__ boff,
                        const int* __restrict__ rp, int* __restrict__ col, int n) {
    __shared__ int lpos[64];
    int b = blockIdx.x;
    int t = threadIdx.x;
    int nd0 = b << BSH;
    if (t < 64 && nd0 + t < n) lpos[t] = rp[nd0 + t];
    __syncthreads();
    int s = boff[b], e = boff[b + 1];
    for (int i = s + t; i < e; i += 256) {
        int2 p = pairs[i];
        int slot = atomicAdd(&lpos[p.y & 63], 1);
        col[slot] = p.x;
    }
}

// -------------------------------------------------------------- converters
struct ConvDesc { const float* w; bf16_t* o; int kin; int kpad; };
struct ConvArgs { ConvDesc d[8]; };

__global__ void conv_w_k(ConvArgs args) {
    ConvDesc d = args.d[blockIdx.y];
    int i = blockIdx.x * 256 + threadIdx.x;
    int tot = 128 * d.kpad;
    if (i >= tot) return;
    int n = i / d.kpad, k = i - n * d.kpad;
    float v = (k < d.kin) ? d.w[(size_t)k * 128 + n] : 0.f;
    d.o[i] = (bf16_t)v;
}

__global__ void conv_x_k(const float* __restrict__ x, bf16_t* __restrict__ xb, int n) {
    int i = blockIdx.x * 256 + threadIdx.x;
    if (i >= n * 64) return;
    int node = i >> 6, k = i & 63;
    xb[i] = (k < D_IN) ? (bf16_t)x[node * D_IN + k] : (bf16_t)0.f;
}

// ------------------------------------------------------------- aggregation
__global__ void agg_bf64_k(const bf16_t* __restrict__ feat, const int* __restrict__ rp,
                           const int* __restrict__ col, bf16_t* __restrict__ mean, int n) {
    int wid = (blockIdx.x * blockDim.x + threadIdx.x) >> 6;
    int lane = threadIdx.x & 63;
    if (wid >= n) return;
    int start = rp[wid], end = rp[wid + 1];
    float a0 = 0.f, a1 = 0.f;
    int e = start;
    for (; e + 3 < end; e += 4) {
        int s0 = col[e], s1 = col[e + 1], s2 = col[e + 2], s3 = col[e + 3];
        float v0 = (float)feat[(size_t)s0 * 64 + lane];
        float v1 = (float)feat[(size_t)s1 * 64 + lane];
        float v2 = (float)feat[(size_t)s2 * 64 + lane];
        float v3 = (float)feat[(size_t)s3 * 64 + lane];
        a0 += v0 + v1;
        a1 += v2 + v3;
    }
    for (; e < end; e++) a0 += (float)feat[(size_t)col[e] * 64 + lane];
    int c = end - start;
    float invc = 1.f / (float)(c > 0 ? c : 1);
    mean[(size_t)wid * 64 + lane] = (bf16_t)((a0 + a1) * invc);
}

__global__ void agg_bf128_k(const bf16_t* __restrict__ feat, const int* __restrict__ rp,
                            const int* __restrict__ col, bf16_t* __restrict__ mean, int n) {
    int wid = (blockIdx.x * blockDim.x + threadIdx.x) >> 6;
    int lane = threadIdx.x & 63;
    if (wid >= n) return;
    int start = rp[wid], end = rp[wid + 1];
    float ax0 = 0.f, ay0 = 0.f, ax1 = 0.f, ay1 = 0.f;
    int e = start;
    for (; e + 3 < end; e += 4) {
        int s0 = col[e], s1 = col[e + 1], s2 = col[e + 2], s3 = col[e + 3];
        bf16x2 v0 = *(const bf16x2*)(feat + (size_t)s0 * 128 + lane * 2);
        bf16x2 v1 = *(const bf16x2*)(feat + (size_t)s1 * 128 + lane * 2);
        bf16x2 v2 = *(const bf16x2*)(feat + (size_t)s2 * 128 + lane * 2);
        bf16x2 v3 = *(const bf16x2*)(feat + (size_t)s3 * 128 + lane * 2);
        ax0 += (float)v0.x + (float)v1.x;
        ay0 += (float)v0.y + (float)v1.y;
        ax1 += (float)v2.x + (float)v3.x;
        ay1 += (float)v2.y + (float)v3.y;
    }
    for (; e < end; e++) {
        bf16x2 v0 = *(const bf16x2*)(feat + (size_t)col[e] * 128 + lane * 2);
        ax0 += (float)v0.x;
        ay0 += (float)v0.y;
    }
    int c = end - start;
    float invc = 1.f / (float)(c > 0 ? c : 1);
    bf16x2 o;
    o.x = (bf16_t)((ax0 + ax1) * invc);
    o.y = (bf16_t)((ay0 + ay1) * invc);
    *(bf16x2*)(mean + (size_t)wid * 128 + lane * 2) = o;
}

// ------------------------------------------------- fused SAGE linear (MFMA)
// out(bf16)[M][128] = A@WlT^T (+ B@WrT^T) + bias. Weights staged to LDS in
// fragment order (conflict-free lane*16 ds_read). One wave = 32 rows.
// LN partials (fp32, pre-rounding) one float2 per wave slot.
template <int KPAD, bool DUAL, bool ACC>
__global__ __launch_bounds__(256) void mfma_gemm_k(
    const bf16_t* __restrict__ A, const bf16_t* __restrict__ B,
    const bf16_t* __restrict__ WlT, const bf16_t* __restrict__ WrT,
    const float* __restrict__ bias,
    bf16_t* __restrict__ out, float2* __restrict__ partials, int M) {
    constexpr int KC = KPAD / 32;
    constexpr int WELE = 8 * KC * 64 * 8;
    __shared__ bf16_t lwl[WELE];
    __shared__ bf16_t lwr[DUAL ? WELE : 8];

    const int tid = threadIdx.x;
    for (int ch = tid; ch < 8 * KC * 64; ch += 256) {
        int nt = ch / (KC * 64);
        int rem = ch - nt * (KC * 64);
        int c = rem >> 6;
        int ln = rem & 63;
        int m = ln & 15, q = ln >> 4;
        size_t srcoff = (size_t)(nt * 16 + m) * KPAD + c * 32 + q * 8;
        *(bf16x8*)&lwl[ch * 8] = *(const bf16x8*)(WlT + srcoff);
        if (DUAL) *(bf16x8*)&lwr[ch * 8] = *(const bf16x8*)(WrT + srcoff);
    }
    __syncthreads();

    const int wid = blockIdx.x * 4 + (tid >> 6);
    const int lane = tid & 63;
    const int row0 = wid * 32;
    if (row0 >= M) return;
    const int m = lane & 15;
    const int q = lane >> 4;

    bf16x8 af[2][KC], bfr[DUAL ? 2 : 1][DUAL ? KC : 1];
#pragma unroll
    for (int s = 0; s < 2; s++) {
        const bf16_t* ar = A + (size_t)(row0 + s * 16 + m) * KPAD + q * 8;
#pragma unroll
        for (int c = 0; c < KC; c++) af[s][c] = *(const bf16x8*)(ar + c * 32);
        if (DUAL) {
            const bf16_t* br = B + (size_t)(row0 + s * 16 + m) * KPAD + q * 8;
#pragma unroll
            for (int c = 0; c < KC; c++) bfr[s][c] = *(const bf16x8*)(br + c * 32);
        }
    }

    float lsum = 0.f, lsum2 = 0.f;
#pragma unroll
    for (int nt = 0; nt < 8; nt++) {
        f32x4_t acc0 = {0.f, 0.f, 0.f, 0.f};
        f32x4_t acc1 = {0.f, 0.f, 0.f, 0.f};
#pragma unroll
        for (int c = 0; c < KC; c++) {
            bf16x8 w = *(const bf16x8*)&lwl[((nt * KC + c) * 64 + lane) * 8];
            acc0 = __builtin_amdgcn_mfma_f32_16x16x32_bf16(af[0][c], w, acc0, 0, 0, 0);
            acc1 = __builtin_amdgcn_mfma_f32_16x16x32_bf16(af[1][c], w, acc1, 0, 0, 0);
        }
        if (DUAL) {
#pragma unroll
            for (int c = 0; c < KC; c++) {
                bf16x8 w = *(const bf16x8*)&lwr[((nt * KC + c) * 64 + lane) * 8];
                acc0 = __builtin_amdgcn_mfma_f32_16x16x32_bf16(bfr[0][c], w, acc0, 0, 0, 0);
                acc1 = __builtin_amdgcn_mfma_f32_16x16x32_bf16(bfr[1][c], w, acc1, 0, 0, 0);
            }
        }
        float bv = bias ? bias[nt * 16 + m] : 0.f;
#pragma unroll
        for (int s = 0; s < 2; s++) {
            f32x4_t* ap = (s == 0) ? &acc0 : &acc1;
#pragma unroll
            for (int r = 0; r < 4; r++) {
                int row = row0 + s * 16 + q * 4 + r;
                if (row < M) {
                    float o = (*ap)[r] + bv;
                    out[(size_t)row * 128 + nt * 16 + m] = (bf16_t)o;
                    if (ACC) { lsum += o; lsum2 += o * o; }
                }
            }
        }
    }
    if (ACC) {
        for (int off = 32; off > 0; off >>= 1) {
            lsum += __shfl_down(lsum, off);
            lsum2 += __shfl_down(lsum2, off);
        }
        if (lane == 0) partials[wid] = make_float2(lsum, lsum2);
    }
}

__global__ void reduce_partials_k(const float2* __restrict__ p, int n,
                                  double* __restrict__ outp) {
    __shared__ double s1[256], s2[256];
    int t = threadIdx.x;
    double a = 0.0, b = 0.0;
    for (int i = t; i < n; i += 256) { a += (double)p[i].x; b += (double)p[i].y; }
    s1[t] = a; s2[t] = b;
    __syncthreads();
    for (int off = 128; off > 0; off >>= 1) {
        if (t < off) { s1[t] += s1[t + off]; s2[t] += s2[t + off]; }
        __syncthreads();
    }
    if (t == 0) { outp[0] = s1[0]; outp[1] = s2[0]; }
}

// --------------------------------------------- LN (graph mode) + PReLU (+skip)
// pre / s are bf16 now. MODE 1: out0=h1(bf16), out1=h1+s(bf16).
// MODE 2: out0 = h1in + prelu(ln(pre)) + s (bf16). MODE 3: out0 = fp32.
template <int MODE>
__global__ void ln_prelu_k(const bf16_t* __restrict__ pre, const bf16_t* __restrict__ h1in,
                           const bf16_t* __restrict__ s,
                           const float* __restrict__ lnw, const float* __restrict__ lnb,
                           const float* __restrict__ a_ptr, const double* __restrict__ acc,
                           void* __restrict__ out0v, void* __restrict__ out1v, int total) {
    int i = blockIdx.x * blockDim.x + threadIdx.x;
    if (i * 4 >= total) return;
    double cinv = 1.0 / (double)total;
    double mm = acc[0] * cinv;
    double var = acc[1] * cinv - mm * mm;
    float stdv = (float)sqrt(var > 0.0 ? var : 0.0);
    float scale = 1.0f / (stdv + LN_EPS);
    float mf = (float)mm;
    float a = a_ptr[0];
    int c4 = i & 31;
    float4 w = ((const float4*)lnw)[c4];
    float4 b = ((const float4*)lnb)[c4];
    bf16x4 p4 = ((const bf16x4*)pre)[i];
    float4 h;
    h.x = ((float)p4.x - mf) * scale * w.x + b.x;
    h.y = ((float)p4.y - mf) * scale * w.y + b.y;
    h.z = ((float)p4.z - mf) * scale * w.z + b.z;
    h.w = ((float)p4.w - mf) * scale * w.w + b.w;
    h.x = h.x >= 0.f ? h.x : a * h.x;
    h.y = h.y >= 0.f ? h.y : a * h.y;
    h.z = h.z >= 0.f ? h.z : a * h.z;
    h.w = h.w >= 0.f ? h.w : a * h.w;
    if (MODE == 1) {
        bf16x4 hb;
        hb.x = (bf16_t)h.x; hb.y = (bf16_t)h.y; hb.z = (bf16_t)h.z; hb.w = (bf16_t)h.w;
        ((bf16x4*)out0v)[i] = hb;
        bf16x4 sv = ((const bf16x4*)s)[i];
        bf16x4 tb;
        tb.x = (bf16_t)(h.x + (float)sv.x); tb.y = (bf16_t)(h.y + (float)sv.y);
        tb.z = (bf16_t)(h.z + (float)sv.z); tb.w = (bf16_t)(h.w + (float)sv.w);
        ((bf16x4*)out1v)[i] = tb;
    } else if (MODE == 2) {
        bf16x4 hv = ((const bf16x4*)h1in)[i];
        bf16x4 sv = ((const bf16x4*)s)[i];
        bf16x4 tb;
        tb.x = (bf16_t)((float)hv.x + h.x + (float)sv.x);
        tb.y = (bf16_t)((float)hv.y + h.y + (float)sv.y);
        tb.z = (bf16_t)((float)hv.z + h.z + (float)sv.z);
        tb.w = (bf16_t)((float)hv.w + h.w + (float)sv.w);
        ((bf16x4*)out0v)[i] = tb;
    } else {
        ((float4*)out0v)[i] = h;
    }
}

// ------------------------------------------------------------------ launch
extern "C" void kernel_launch(void* const* d_in, const int* in_sizes, int n_in,
                              void* d_out, int out_size, void* d_ws, size_t ws_size,
                              hipStream_t stream) {
    const float* x    = (const float*)d_in[0];
    const int*   esrc = (const int*)d_in[1];
    const int*   edst = (const int*)d_in[2];
    const float* Wl1  = (const float*)d_in[3];
    const float* Wr1  = (const float*)d_in[4];
    const float* b1   = (const float*)d_in[5];
    const float* Wl2  = (const float*)d_in[6];
    const float* Wr2  = (const float*)d_in[7];
    const float* b2   = (const float*)d_in[8];
    const float* Wl3  = (const float*)d_in[9];
    const float* Wr3  = (const float*)d_in[10];
    const float* b3   = (const float*)d_in[11];
    const float* Ws1  = (const float*)d_in[12];
    const float* Ws2  = (const float*)d_in[13];
    const float* lnw1 = (const float*)d_in[14];
    const float* lnb1 = (const float*)d_in[15];
    const float* lnw2 = (const float*)d_in[16];
    const float* lnb2 = (const float*)d_in[17];
    const float* lnw3 = (const float*)d_in[18];
    const float* lnb3 = (const float*)d_in[19];
    const float* a1   = (const float*)d_in[20];
    const float* a2   = (const float*)d_in[21];
    const float* a3   = (const float*)d_in[22];

    const int N = in_sizes[0] / D_IN;
    const int E = in_sizes[1];
    const int NB = (N + 63) >> BSH;   // buckets of 64 nodes

    char* ws = (char*)d_ws;
    size_t off = 0;
    auto alloc = [&](size_t bytes) -> void* {
        void* p = ws + off;
        off += (bytes + 255) & ~(size_t)255;
        return p;
    };
    bf16_t* xb   = (bf16_t*)alloc((size_t)N * 64 * 2);
    bf16_t* mean = (bf16_t*)alloc((size_t)N * 128 * 2);
    bf16_t* PRE  = (bf16_t*)alloc((size_t)N * 128 * 2);
    bf16_t* C    = (bf16_t*)alloc((size_t)N * 128 * 2);
    bf16_t* h1b  = (bf16_t*)alloc((size_t)N * 128 * 2);
    bf16_t* TB   = (bf16_t*)alloc((size_t)N * 128 * 2);
    bf16_t* WT   = (bf16_t*)alloc((size_t)(4 * 128 * 64 + 4 * 128 * 128) * 2);
    int* cnt  = (int*)alloc((size_t)N * 4);
    int* rp   = (int*)alloc((size_t)(N + 1) * 4);
    int* pos  = (int*)alloc((size_t)N * 4);
    int* col  = (int*)alloc((size_t)E * 4);
    int* part = (int*)alloc(512);
    int* bcnt = (int*)alloc((size_t)NB * 4);
    int* boff = (int*)alloc((size_t)(NB + 1) * 4);
    int* bpos = (int*)alloc((size_t)NB * 4);
    int2* pairs = (int2*)alloc((size_t)E * 8);
    double* lnacc = (double*)alloc(6 * 8);
    const int tiles = (N + 31) / 32;
    float2* partials = (float2*)alloc((size_t)tiles * 8);

    bf16_t* Wl1T = WT;
    bf16_t* Wr1T = Wl1T + 128 * 64;
    bf16_t* Ws1T = Wr1T + 128 * 64;
    bf16_t* Ws2T = Ws1T + 128 * 64;
    bf16_t* Wl2T = Ws2T + 128 * 64;
    bf16_t* Wr2T = Wl2T + 128 * 128;
    bf16_t* Wl3T = Wr2T + 128 * 128;
    bf16_t* Wr3T = Wl3T + 128 * 128;

    hipMemsetAsync(bcnt, 0, (size_t)NB * 4, stream);

    // --- bucketed CSR build
    const int NBS_b = (NB + 1023) / 1024;
    const int NBS_n = (N + 1023) / 1024;
    hist_b_k<<<(E + 255) / 256, 256, 0, stream>>>(edst, bcnt, E);
    scan_partial_k<<<NBS_b, 256, 0, stream>>>(bcnt, part, NB);
    scan_root_k<<<1, 64, 0, stream>>>(part, NBS_b);
    scan_final_k<<<NBS_b, 256, 0, stream>>>(bcnt, part, boff, bpos, NB);
    bfill_k<<<(E + 255) / 256, 256, 0, stream>>>(esrc, edst, bpos, pairs, E);
    nhist_k<<<NB, 256, 0, stream>>>(pairs, boff, cnt, N);
    scan_partial_k<<<NBS_n, 256, 0, stream>>>(cnt, part, N);
    scan_root_k<<<1, 64, 0, stream>>>(part, NBS_n);
    scan_final_k<<<NBS_n, 256, 0, stream>>>(cnt, part, rp, pos, N);
    cfill_k<<<NB, 256, 0, stream>>>(pairs, boff, rp, col, N);

    // --- weight/feature conversion
    ConvArgs ca;
    ca.d[0] = {Wl1, Wl1T, 50, 64};
    ca.d[1] = {Wr1, Wr1T, 50, 64};
    ca.d[2] = {Ws1, Ws1T, 50, 64};
    ca.d[3] = {Ws2, Ws2T, 50, 64};
    ca.d[4] = {Wl2, Wl2T, 128, 128};
    ca.d[5] = {Wr2, Wr2T, 128, 128};
    ca.d[6] = {Wl3, Wl3T, 128, 128};
    ca.d[7] = {Wr3, Wr3T, 128, 128};
    conv_w_k<<<dim3(64, 8), 256, 0, stream>>>(ca);
    conv_x_k<<<(N * 64 + 255) / 256, 256, 0, stream>>>(x, xb, N);

    const int aggBlocks = ((N * 64) + 255) / 256;
    const int gemmBlocks = (tiles + 3) / 4;
    const int lnBlocks = (N * 128 / 4 + 255) / 256;
    const int total = N * 128;

    // ---- layer 1
    agg_bf64_k<<<aggBlocks, 256, 0, stream>>>(xb, rp, col, mean, N);
    mfma_gemm_k<64, true, true><<<gemmBlocks, 256, 0, stream>>>(
        mean, xb, Wl1T, Wr1T, b1, PRE, partials, N);
    reduce_partials_k<<<1, 256, 0, stream>>>(partials, tiles, lnacc + 0);
    mfma_gemm_k<64, false, false><<<gemmBlocks, 256, 0, stream>>>(
        xb, nullptr, Ws1T, nullptr, nullptr, C, nullptr, N);
    ln_prelu_k<1><<<lnBlocks, 256, 0, stream>>>(
        PRE, nullptr, C, lnw1, lnb1, a1, lnacc + 0, h1b, TB, total);

    // ---- layer 2
    agg_bf128_k<<<aggBlocks, 256, 0, stream>>>(TB, rp, col, mean, N);
    mfma_gemm_k<64, false, false><<<gemmBlocks, 256, 0, stream>>>(
        xb, nullptr, Ws2T, nullptr, nullptr, C, nullptr, N);
    mfma_gemm_k<128, true, true><<<gemmBlocks, 256, 0, stream>>>(
        mean, TB, Wl2T, Wr2T, b2, PRE, partials, N);
    reduce_partials_k<<<1, 256, 0, stream>>>(partials, tiles, lnacc + 2);
    ln_prelu_k<2><<<lnBlocks, 256, 0, stream>>>(
        PRE, h1b, C, lnw2, lnb2, a2, lnacc + 2, TB, nullptr, total);

    // ---- layer 3
    agg_bf128_k<<<aggBlocks, 256, 0, stream>>>(TB, rp, col, mean, N);
    mfma_gemm_k<128, true, true><<<gemmBlocks, 256, 0, stream>>>(
        mean, TB, Wl3T, Wr3T, b3, PRE, partials, N);
    reduce_partials_k<<<1, 256, 0, stream>>>(partials, tiles, lnacc + 4);
    ln_prelu_k<3><<<lnBlocks, 256, 0, stream>>>(
        PRE, nullptr, nullptr, lnw3, lnb3, a3, lnacc + 4, d_out, nullptr, total);
}

// Round 5
// 613.537 us; speedup vs baseline: 1.6976x; 1.6976x over previous
//
#include <hip/hip_runtime.h>

#define D_IN 50
#define LN_EPS 1e-5f
#define BSH 8           // 256 nodes per bucket
#define MAXB 512        // max buckets (N <= 131072)

typedef __bf16 bf16_t;
typedef bf16_t bf16x8 __attribute__((ext_vector_type(8)));
typedef bf16_t bf16x4 __attribute__((ext_vector_type(4)));
typedef bf16_t bf16x2 __attribute__((ext_vector_type(2)));
typedef float f32x4_t __attribute__((ext_vector_type(4)));

// ---------------------------------------------------------------- CSR build
// Phase A: bucket histogram, block-local LDS pre-aggregation; global
// counters padded to one per 64B line (stride 16 ints).
__global__ void bucket_hist_k(const int* __restrict__ dst, int* __restrict__ bcnt,
                              int e, int nb) {
    __shared__ int lh[MAXB];
    int t = threadIdx.x;
    for (int i = t; i < nb; i += 256) lh[i] = 0;
    __syncthreads();
    for (int i = blockIdx.x * 256 + t; i < e; i += gridDim.x * 256)
        atomicAdd(&lh[dst[i] >> BSH], 1);
    __syncthreads();
    for (int i = t; i < nb; i += 256) {
        int c = lh[i];
        if (c) atomicAdd(&bcnt[i * 16], c);
    }
}

// Phase B: single-block scan over <=512 buckets -> boff (+ init padded bpos)
__global__ void bscan_k(const int* __restrict__ bcnt, int* __restrict__ boff,
                        int* __restrict__ bpos, int nb, int e) {
    __shared__ int l[MAXB];
    int t = threadIdx.x;  // 512 threads
    l[t] = (t < nb) ? bcnt[t * 16] : 0;
    __syncthreads();
    for (int off = 1; off < MAXB; off <<= 1) {
        int v = (t >= off) ? l[t - off] : 0;
        __syncthreads();
        l[t] += v;
        __syncthreads();
    }
    int excl = (t > 0) ? l[t - 1] : 0;
    if (t < nb) { boff[t] = excl; bpos[t * 16] = excl; }
    if (t == 0) boff[nb] = e;
}

// Phase C: scatter edges into bucket regions. Per-block: LDS histogram of its
// contiguous chunk, ONE reservation atomic per touched bucket, then place via
// LDS cursors. Pool entry: src (17b) | local_dst (8b) << 17.
__global__ void scatter_k(const int* __restrict__ src, const int* __restrict__ dst,
                          int* __restrict__ bpos, unsigned* __restrict__ pool,
                          int e, int nb) {
    __shared__ int lh[MAXB];
    __shared__ int lcur[MAXB];
    int t = threadIdx.x;
    for (int i = t; i < nb; i += 256) lh[i] = 0;
    __syncthreads();
    int chunk = (e + gridDim.x - 1) / gridDim.x;
    int s = blockIdx.x * chunk;
    int en = min(e, s + chunk);
    for (int i = s + t; i < en; i += 256)
        atomicAdd(&lh[dst[i] >> BSH], 1);
    __syncthreads();
    for (int i = t; i < nb; i += 256) {
        int c = lh[i];
        lcur[i] = c ? atomicAdd(&bpos[i * 16], c) : 0;
    }
    __syncthreads();
    for (int i = s + t; i < en; i += 256) {
        int d = dst[i];
        int p = atomicAdd(&lcur[d >> BSH], 1);
        pool[p] = (unsigned)src[i] | ((unsigned)(d & 255) << 17);
    }
}

// Phase D: per-bucket node histogram (LDS), coalesced cnt writes
__global__ void nhist_k(const unsigned* __restrict__ pool, const int* __restrict__ boff,
                        int* __restrict__ cnt, int n) {
    __shared__ int lc[256];
    int b = blockIdx.x, t = threadIdx.x;
    lc[t] = 0;
    __syncthreads();
    int s = boff[b], e = boff[b + 1];
    for (int i = s + t; i < e; i += 256) atomicAdd(&lc[pool[i] >> 17], 1);
    __syncthreads();
    int nd = (b << BSH) + t;
    if (nd < n) cnt[nd] = lc[t];
}

__global__ void scan_partial_k(const int* __restrict__ cnt, int* __restrict__ part, int n) {
    __shared__ int lds[256];
    int base = blockIdx.x * 1024;
    int t = threadIdx.x;
    int s = 0;
    for (int j = 0; j < 4; j++) {
        int idx = base + t * 4 + j;
        if (idx < n) s += cnt[idx];
    }
    lds[t] = s;
    __syncthreads();
    for (int off = 128; off > 0; off >>= 1) {
        if (t < off) lds[t] += lds[t + off];
        __syncthreads();
    }
    if (t == 0) part[blockIdx.x] = lds[0];
}

__global__ void scan_root_k(int* part, int nb) {
    if (threadIdx.x == 0 && blockIdx.x == 0) {
        int run = 0;
        for (int i = 0; i < nb; i++) { int v = part[i]; part[i] = run; run += v; }
    }
}

__global__ void scan_final_k(const int* __restrict__ cnt, const int* __restrict__ part,
                             int* __restrict__ row_ptr, int n) {
    __shared__ int lds[256];
    int base = blockIdx.x * 1024;
    int t = threadIdx.x;
    int v[4];
    int s = 0;
    for (int j = 0; j < 4; j++) {
        int idx = base + t * 4 + j;
        v[j] = (idx < n) ? cnt[idx] : 0;
        s += v[j];
    }
    lds[t] = s;
    __syncthreads();
    for (int off = 1; off < 256; off <<= 1) {
        int xv = (t >= off) ? lds[t - off] : 0;
        __syncthreads();
        lds[t] += xv;
        __syncthreads();
    }
    int ex = (t > 0 ? lds[t - 1] : 0) + part[blockIdx.x];
    for (int j = 0; j < 4; j++) {
        int idx = base + t * 4 + j;
        if (idx < n) {
            row_ptr[idx] = ex;
            if (idx == n - 1) row_ptr[n] = ex + v[j];
            ex += v[j];
        }
    }
}

// Phase E: per-bucket col fill; LDS position cursors; col writes are a
// contiguous ~64KB span per block (single-CU locality, full lines).
__global__ void cfill_k(const unsigned* __restrict__ pool, const int* __restrict__ boff,
                        const int* __restrict__ rp, int* __restrict__ col, int n) {
    __shared__ int lpos[256];
    int b = blockIdx.x, t = threadIdx.x;
    int nd = (b << BSH) + t;
    lpos[t] = (nd < n) ? rp[nd] : 0;
    __syncthreads();
    int s = boff[b], e = boff[b + 1];
    for (int i = s + t; i < e; i += 256) {
        unsigned pk = pool[i];
        int slot = atomicAdd(&lpos[pk >> 17], 1);
        col[slot] = (int)(pk & 0x1FFFFu);
    }
}

// -------------------------------------------------------------- converters
struct ConvDesc { const float* w; bf16_t* o; int kin; int kpad; };
struct ConvArgs { ConvDesc d[8]; };

__global__ void conv_w_k(ConvArgs args) {
    ConvDesc d = args.d[blockIdx.y];
    int i = blockIdx.x * 256 + threadIdx.x;
    int tot = 128 * d.kpad;
    if (i >= tot) return;
    int n = i / d.kpad, k = i - n * d.kpad;
    float v = (k < d.kin) ? d.w[(size_t)k * 128 + n] : 0.f;
    d.o[i] = (bf16_t)v;
}

__global__ void conv_x_k(const float* __restrict__ x, bf16_t* __restrict__ xb, int n) {
    int i = blockIdx.x * 256 + threadIdx.x;
    if (i >= n * 64) return;
    int node = i >> 6, k = i & 63;
    xb[i] = (k < D_IN) ? (bf16_t)x[node * D_IN + k] : (bf16_t)0.f;
}

// ------------------------------------------------------------- aggregation
__global__ void agg_bf64_k(const bf16_t* __restrict__ feat, const int* __restrict__ rp,
                           const int* __restrict__ col, bf16_t* __restrict__ mean, int n) {
    int wid = (blockIdx.x * blockDim.x + threadIdx.x) >> 6;
    int lane = threadIdx.x & 63;
    if (wid >= n) return;
    int start = rp[wid], end = rp[wid + 1];
    float a0 = 0.f, a1 = 0.f;
    int e = start;
    for (; e + 3 < end; e += 4) {
        int s0 = col[e], s1 = col[e + 1], s2 = col[e + 2], s3 = col[e + 3];
        float v0 = (float)feat[(size_t)s0 * 64 + lane];
        float v1 = (float)feat[(size_t)s1 * 64 + lane];
        float v2 = (float)feat[(size_t)s2 * 64 + lane];
        float v3 = (float)feat[(size_t)s3 * 64 + lane];
        a0 += v0 + v1;
        a1 += v2 + v3;
    }
    for (; e < end; e++) a0 += (float)feat[(size_t)col[e] * 64 + lane];
    int c = end - start;
    float invc = 1.f / (float)(c > 0 ? c : 1);
    mean[(size_t)wid * 64 + lane] = (bf16_t)((a0 + a1) * invc);
}

__global__ void agg_bf128_k(const bf16_t* __restrict__ feat, const int* __restrict__ rp,
                            const int* __restrict__ col, bf16_t* __restrict__ mean, int n) {
    int wid = (blockIdx.x * blockDim.x + threadIdx.x) >> 6;
    int lane = threadIdx.x & 63;
    if (wid >= n) return;
    int start = rp[wid], end = rp[wid + 1];
    float ax0 = 0.f, ay0 = 0.f, ax1 = 0.f, ay1 = 0.f;
    int e = start;
    for (; e + 3 < end; e += 4) {
        int s0 = col[e], s1 = col[e + 1], s2 = col[e + 2], s3 = col[e + 3];
        bf16x2 v0 = *(const bf16x2*)(feat + (size_t)s0 * 128 + lane * 2);
        bf16x2 v1 = *(const bf16x2*)(feat + (size_t)s1 * 128 + lane * 2);
        bf16x2 v2 = *(const bf16x2*)(feat + (size_t)s2 * 128 + lane * 2);
        bf16x2 v3 = *(const bf16x2*)(feat + (size_t)s3 * 128 + lane * 2);
        ax0 += (float)v0.x + (float)v1.x;
        ay0 += (float)v0.y + (float)v1.y;
        ax1 += (float)v2.x + (float)v3.x;
        ay1 += (float)v2.y + (float)v3.y;
    }
    for (; e < end; e++) {
        bf16x2 v0 = *(const bf16x2*)(feat + (size_t)col[e] * 128 + lane * 2);
        ax0 += (float)v0.x;
        ay0 += (float)v0.y;
    }
    int c = end - start;
    float invc = 1.f / (float)(c > 0 ? c : 1);
    bf16x2 o;
    o.x = (bf16_t)((ax0 + ax1) * invc);
    o.y = (bf16_t)((ay0 + ay1) * invc);
    *(bf16x2*)(mean + (size_t)wid * 128 + lane * 2) = o;
}

// ------------------------------------------------- fused SAGE linear (MFMA)
template <int KPAD, bool DUAL, bool ACC>
__global__ __launch_bounds__(256) void mfma_gemm_k(
    const bf16_t* __restrict__ A, const bf16_t* __restrict__ B,
    const bf16_t* __restrict__ WlT, const bf16_t* __restrict__ WrT,
    const float* __restrict__ bias,
    bf16_t* __restrict__ out, float2* __restrict__ partials, int M) {
    constexpr int KC = KPAD / 32;
    constexpr int WELE = 8 * KC * 64 * 8;
    __shared__ bf16_t lwl[WELE];
    __shared__ bf16_t lwr[DUAL ? WELE : 8];

    const int tid = threadIdx.x;
    for (int ch = tid; ch < 8 * KC * 64; ch += 256) {
        int nt = ch / (KC * 64);
        int rem = ch - nt * (KC * 64);
        int c = rem >> 6;
        int ln = rem & 63;
        int m = ln & 15, q = ln >> 4;
        size_t srcoff = (size_t)(nt * 16 + m) * KPAD + c * 32 + q * 8;
        *(bf16x8*)&lwl[ch * 8] = *(const bf16x8*)(WlT + srcoff);
        if (DUAL) *(bf16x8*)&lwr[ch * 8] = *(const bf16x8*)(WrT + srcoff);
    }
    __syncthreads();

    const int wid = blockIdx.x * 4 + (tid >> 6);
    const int lane = tid & 63;
    const int row0 = wid * 32;
    if (row0 >= M) return;
    const int m = lane & 15;
    const int q = lane >> 4;

    bf16x8 af[2][KC], bfr[DUAL ? 2 : 1][DUAL ? KC : 1];
#pragma unroll
    for (int s = 0; s < 2; s++) {
        const bf16_t* ar = A + (size_t)(row0 + s * 16 + m) * KPAD + q * 8;
#pragma unroll
        for (int c = 0; c < KC; c++) af[s][c] = *(const bf16x8*)(ar + c * 32);
        if (DUAL) {
            const bf16_t* br = B + (size_t)(row0 + s * 16 + m) * KPAD + q * 8;
#pragma unroll
            for (int c = 0; c < KC; c++) bfr[s][c] = *(const bf16x8*)(br + c * 32);
        }
    }

    float lsum = 0.f, lsum2 = 0.f;
#pragma unroll
    for (int nt = 0; nt < 8; nt++) {
        f32x4_t acc0 = {0.f, 0.f, 0.f, 0.f};
        f32x4_t acc1 = {0.f, 0.f, 0.f, 0.f};
#pragma unroll
        for (int c = 0; c < KC; c++) {
            bf16x8 w = *(const bf16x8*)&lwl[((nt * KC + c) * 64 + lane) * 8];
            acc0 = __builtin_amdgcn_mfma_f32_16x16x32_bf16(af[0][c], w, acc0, 0, 0, 0);
            acc1 = __builtin_amdgcn_mfma_f32_16x16x32_bf16(af[1][c], w, acc1, 0, 0, 0);
        }
        if (DUAL) {
#pragma unroll
            for (int c = 0; c < KC; c++) {
                bf16x8 w = *(const bf16x8*)&lwr[((nt * KC + c) * 64 + lane) * 8];
                acc0 = __builtin_amdgcn_mfma_f32_16x16x32_bf16(bfr[0][c], w, acc0, 0, 0, 0);
                acc1 = __builtin_amdgcn_mfma_f32_16x16x32_bf16(bfr[1][c], w, acc1, 0, 0, 0);
            }
        }
        float bv = bias ? bias[nt * 16 + m] : 0.f;
#pragma unroll
        for (int s = 0; s < 2; s++) {
            f32x4_t* ap = (s == 0) ? &acc0 : &acc1;
#pragma unroll
            for (int r = 0; r < 4; r++) {
                int row = row0 + s * 16 + q * 4 + r;
                if (row < M) {
                    float o = (*ap)[r] + bv;
                    out[(size_t)row * 128 + nt * 16 + m] = (bf16_t)o;
                    if (ACC) { lsum += o; lsum2 += o * o; }
                }
            }
        }
    }
    if (ACC) {
        for (int off = 32; off > 0; off >>= 1) {
            lsum += __shfl_down(lsum, off);
            lsum2 += __shfl_down(lsum2, off);
        }
        if (lane == 0) partials[wid] = make_float2(lsum, lsum2);
    }
}

__global__ void reduce_partials_k(const float2* __restrict__ p, int n,
                                  double* __restrict__ outp) {
    __shared__ double s1[256], s2[256];
    int t = threadIdx.x;
    double a = 0.0, b = 0.0;
    for (int i = t; i < n; i += 256) { a += (double)p[i].x; b += (double)p[i].y; }
    s1[t] = a; s2[t] = b;
    __syncthreads();
    for (int off = 128; off > 0; off >>= 1) {
        if (t < off) { s1[t] += s1[t + off]; s2[t] += s2[t + off]; }
        __syncthreads();
    }
    if (t == 0) { outp[0] = s1[0]; outp[1] = s2[0]; }
}

// --------------------------------------------- LN (graph mode) + PReLU (+skip)
template <int MODE>
__global__ void ln_prelu_k(const bf16_t* __restrict__ pre, const bf16_t* __restrict__ h1in,
                           const bf16_t* __restrict__ s,
                           const float* __restrict__ lnw, const float* __restrict__ lnb,
                           const float* __restrict__ a_ptr, const double* __restrict__ acc,
                           void* __restrict__ out0v, void* __restrict__ out1v, int total) {
    int i = blockIdx.x * blockDim.x + threadIdx.x;
    if (i * 4 >= total) return;
    double cinv = 1.0 / (double)total;
    double mm = acc[0] * cinv;
    double var = acc[1] * cinv - mm * mm;
    float stdv = (float)sqrt(var > 0.0 ? var : 0.0);
    float scale = 1.0f / (stdv + LN_EPS);
    float mf = (float)mm;
    float a = a_ptr[0];
    int c4 = i & 31;
    float4 w = ((const float4*)lnw)[c4];
    float4 b = ((const float4*)lnb)[c4];
    bf16x4 p4 = ((const bf16x4*)pre)[i];
    float4 h;
    h.x = ((float)p4.x - mf) * scale * w.x + b.x;
    h.y = ((float)p4.y - mf) * scale * w.y + b.y;
    h.z = ((float)p4.z - mf) * scale * w.z + b.z;
    h.w = ((float)p4.w - mf) * scale * w.w + b.w;
    h.x = h.x >= 0.f ? h.x : a * h.x;
    h.y = h.y >= 0.f ? h.y : a * h.y;
    h.z = h.z >= 0.f ? h.z : a * h.z;
    h.w = h.w >= 0.f ? h.w : a * h.w;
    if (MODE == 1) {
        bf16x4 hb;
        hb.x = (bf16_t)h.x; hb.y = (bf16_t)h.y; hb.z = (bf16_t)h.z; hb.w = (bf16_t)h.w;
        ((bf16x4*)out0v)[i] = hb;
        bf16x4 sv = ((const bf16x4*)s)[i];
        bf16x4 tb;
        tb.x = (bf16_t)(h.x + (float)sv.x); tb.y = (bf16_t)(h.y + (float)sv.y);
        tb.z = (bf16_t)(h.z + (float)sv.z); tb.w = (bf16_t)(h.w + (float)sv.w);
        ((bf16x4*)out1v)[i] = tb;
    } else if (MODE == 2) {
        bf16x4 hv = ((const bf16x4*)h1in)[i];
        bf16x4 sv = ((const bf16x4*)s)[i];
        bf16x4 tb;
        tb.x = (bf16_t)((float)hv.x + h.x + (float)sv.x);
        tb.y = (bf16_t)((float)hv.y + h.y + (float)sv.y);
        tb.z = (bf16_t)((float)hv.z + h.z + (float)sv.z);
        tb.w = (bf16_t)((float)hv.w + h.w + (float)sv.w);
        ((bf16x4*)out0v)[i] = tb;
    } else {
        ((float4*)out0v)[i] = h;
    }
}

// ------------------------------------------------------------------ launch
extern "C" void kernel_launch(void* const* d_in, const int* in_sizes, int n_in,
                              void* d_out, int out_size, void* d_ws, size_t ws_size,
                              hipStream_t stream) {
    const float* x    = (const float*)d_in[0];
    const int*   esrc = (const int*)d_in[1];
    const int*   edst = (const int*)d_in[2];
    const float* Wl1  = (const float*)d_in[3];
    const float* Wr1  = (const float*)d_in[4];
    const float* b1   = (const float*)d_in[5];
    const float* Wl2  = (const float*)d_in[6];
    const float* Wr2  = (const float*)d_in[7];
    const float* b2   = (const float*)d_in[8];
    const float* Wl3  = (const float*)d_in[9];
    const float* Wr3  = (const float*)d_in[10];
    const float* b3   = (const float*)d_in[11];
    const float* Ws1  = (const float*)d_in[12];
    const float* Ws2  = (const float*)d_in[13];
    const float* lnw1 = (const float*)d_in[14];
    const float* lnb1 = (const float*)d_in[15];
    const float* lnw2 = (const float*)d_in[16];
    const float* lnb2 = (const float*)d_in[17];
    const float* lnw3 = (const float*)d_in[18];
    const float* lnb3 = (const float*)d_in[19];
    const float* a1   = (const float*)d_in[20];
    const float* a2   = (const float*)d_in[21];
    const float* a3   = (const float*)d_in[22];

    const int N = in_sizes[0] / D_IN;
    const int E = in_sizes[1];
    const int NB = (N + 255) >> BSH;  // 256-node buckets

    char* ws = (char*)d_ws;
    size_t off = 0;
    auto alloc = [&](size_t bytes) -> void* {
        void* p = ws + off;
        off += (bytes + 255) & ~(size_t)255;
        return p;
    };
    bf16_t* xb   = (bf16_t*)alloc((size_t)N * 64 * 2);
    bf16_t* mean = (bf16_t*)alloc((size_t)N * 128 * 2);
    bf16_t* PRE  = (bf16_t*)alloc((size_t)N * 128 * 2);
    bf16_t* C    = (bf16_t*)alloc((size_t)N * 128 * 2);
    bf16_t* h1b  = (bf16_t*)alloc((size_t)N * 128 * 2);
    bf16_t* TB   = (bf16_t*)alloc((size_t)N * 128 * 2);
    bf16_t* WT   = (bf16_t*)alloc((size_t)(4 * 128 * 64 + 4 * 128 * 128) * 2);
    int* cnt  = (int*)alloc((size_t)N * 4);
    int* rp   = (int*)alloc((size_t)(N + 1) * 4);
    int* col  = (int*)alloc((size_t)E * 4);
    int* part = (int*)alloc(512);
    int* bcnt = (int*)alloc((size_t)MAXB * 16 * 4);  // padded: 1 counter / 64B
    int* boff = (int*)alloc((size_t)(MAXB + 1) * 4);
    int* bpos = (int*)alloc((size_t)MAXB * 16 * 4);  // padded
    unsigned* pool = (unsigned*)alloc((size_t)E * 4);
    double* lnacc = (double*)alloc(6 * 8);
    const int tiles = (N + 31) / 32;
    float2* partials = (float2*)alloc((size_t)tiles * 8);

    bf16_t* Wl1T = WT;
    bf16_t* Wr1T = Wl1T + 128 * 64;
    bf16_t* Ws1T = Wr1T + 128 * 64;
    bf16_t* Ws2T = Ws1T + 128 * 64;
    bf16_t* Wl2T = Ws2T + 128 * 64;
    bf16_t* Wr2T = Wl2T + 128 * 128;
    bf16_t* Wl3T = Wr2T + 128 * 128;
    bf16_t* Wr3T = Wl3T + 128 * 128;

    hipMemsetAsync(bcnt, 0, (size_t)MAXB * 16 * 4, stream);

    // --- bucketed CSR build (block-local aggregation, padded counters)
    const int NBS_n = (N + 1023) / 1024;
    bucket_hist_k<<<256, 256, 0, stream>>>(edst, bcnt, E, NB);
    bscan_k<<<1, MAXB, 0, stream>>>(bcnt, boff, bpos, NB, E);
    scatter_k<<<256, 256, 0, stream>>>(esrc, edst, bpos, pool, E, NB);
    nhist_k<<<NB, 256, 0, stream>>>(pool, boff, cnt, N);
    scan_partial_k<<<NBS_n, 256, 0, stream>>>(cnt, part, N);
    scan_root_k<<<1, 64, 0, stream>>>(part, NBS_n);
    scan_final_k<<<NBS_n, 256, 0, stream>>>(cnt, part, rp, N);
    cfill_k<<<NB, 256, 0, stream>>>(pool, boff, rp, col, N);

    // --- weight/feature conversion
    ConvArgs ca;
    ca.d[0] = {Wl1, Wl1T, 50, 64};
    ca.d[1] = {Wr1, Wr1T, 50, 64};
    ca.d[2] = {Ws1, Ws1T, 50, 64};
    ca.d[3] = {Ws2, Ws2T, 50, 64};
    ca.d[4] = {Wl2, Wl2T, 128, 128};
    ca.d[5] = {Wr2, Wr2T, 128, 128};
    ca.d[6] = {Wl3, Wl3T, 128, 128};
    ca.d[7] = {Wr3, Wr3T, 128, 128};
    conv_w_k<<<dim3(64, 8), 256, 0, stream>>>(ca);
    conv_x_k<<<(N * 64 + 255) / 256, 256, 0, stream>>>(x, xb, N);

    const int aggBlocks = ((N * 64) + 255) / 256;
    const int gemmBlocks = (tiles + 3) / 4;
    const int lnBlocks = (N * 128 / 4 + 255) / 256;
    const int total = N * 128;

    // ---- layer 1
    agg_bf64_k<<<aggBlocks, 256, 0, stream>>>(xb, rp, col, mean, N);
    mfma_gemm_k<64, true, true><<<gemmBlocks, 256, 0, stream>>>(
        mean, xb, Wl1T, Wr1T, b1, PRE, partials, N);
    reduce_partials_k<<<1, 256, 0, stream>>>(partials, tiles, lnacc + 0);
    mfma_gemm_k<64, false, false><<<gemmBlocks, 256, 0, stream>>>(
        xb, nullptr, Ws1T, nullptr, nullptr, C, nullptr, N);
    ln_prelu_k<1><<<lnBlocks, 256, 0, stream>>>(
        PRE, nullptr, C, lnw1, lnb1, a1, lnacc + 0, h1b, TB, total);

    // ---- layer 2
    agg_bf128_k<<<aggBlocks, 256, 0, stream>>>(TB, rp, col, mean, N);
    mfma_gemm_k<64, false, false><<<gemmBlocks, 256, 0, stream>>>(
        xb, nullptr, Ws2T, nullptr, nullptr, C, nullptr, N);
    mfma_gemm_k<128, true, true><<<gemmBlocks, 256, 0, stream>>>(
        mean, TB, Wl2T, Wr2T, b2, PRE, partials, N);
    reduce_partials_k<<<1, 256, 0, stream>>>(partials, tiles, lnacc + 2);
    ln_prelu_k<2><<<lnBlocks, 256, 0, stream>>>(
        PRE, h1b, C, lnw2, lnb2, a2, lnacc + 2, TB, nullptr, total);

    // ---- layer 3
    agg_bf128_k<<<aggBlocks, 256, 0, stream>>>(TB, rp, col, mean, N);
    mfma_gemm_k<128, true, true><<<gemmBlocks, 256, 0, stream>>>(
        mean, TB, Wl3T, Wr3T, b3, PRE, partials, N);
    reduce_partials_k<<<1, 256, 0, stream>>>(partials, tiles, lnacc + 4);
    ln_prelu_k<3><<<lnBlocks, 256, 0, stream>>>(
        PRE, nullptr, nullptr, lnw3, lnb3, a3, lnacc + 4, d_out, nullptr, total);
}

// Round 6
// 579.712 us; speedup vs baseline: 1.7967x; 1.0583x over previous
//
#include <hip/hip_runtime.h>

#define D_IN 50
#define LN_EPS 1e-5f
#define BSH 8           // 256 nodes per bucket
#define MAXB 512        // max buckets (N <= 131072)

typedef __bf16 bf16_t;
typedef bf16_t bf16x8 __attribute__((ext_vector_type(8)));
typedef bf16_t bf16x4 __attribute__((ext_vector_type(4)));
typedef bf16_t bf16x2 __attribute__((ext_vector_type(2)));
typedef float f32x4_t __attribute__((ext_vector_type(4)));

// ---------------------------------------------------------------- CSR build
__global__ void bucket_hist_k(const int* __restrict__ dst, int* __restrict__ bcnt,
                              int e, int nb) {
    __shared__ int lh[MAXB];
    int t = threadIdx.x;
    for (int i = t; i < nb; i += 256) lh[i] = 0;
    __syncthreads();
    for (int i = blockIdx.x * 256 + t; i < e; i += gridDim.x * 256)
        atomicAdd(&lh[dst[i] >> BSH], 1);
    __syncthreads();
    for (int i = t; i < nb; i += 256) {
        int c = lh[i];
        if (c) atomicAdd(&bcnt[i * 16], c);
    }
}

__global__ void bscan_k(const int* __restrict__ bcnt, int* __restrict__ boff,
                        int* __restrict__ bpos, int nb, int e) {
    __shared__ int l[MAXB];
    int t = threadIdx.x;
    l[t] = (t < nb) ? bcnt[t * 16] : 0;
    __syncthreads();
    for (int off = 1; off < MAXB; off <<= 1) {
        int v = (t >= off) ? l[t - off] : 0;
        __syncthreads();
        l[t] += v;
        __syncthreads();
    }
    int excl = (t > 0) ? l[t - 1] : 0;
    if (t < nb) { boff[t] = excl; bpos[t * 16] = excl; }
    if (t == 0) boff[nb] = e;
}

__global__ void scatter_k(const int* __restrict__ src, const int* __restrict__ dst,
                          int* __restrict__ bpos, unsigned* __restrict__ pool,
                          int e, int nb) {
    __shared__ int lh[MAXB];
    __shared__ int lcur[MAXB];
    int t = threadIdx.x;
    for (int i = t; i < nb; i += 256) lh[i] = 0;
    __syncthreads();
    int chunk = (e + gridDim.x - 1) / gridDim.x;
    int s = blockIdx.x * chunk;
    int en = min(e, s + chunk);
    for (int i = s + t; i < en; i += 256)
        atomicAdd(&lh[dst[i] >> BSH], 1);
    __syncthreads();
    for (int i = t; i < nb; i += 256) {
        int c = lh[i];
        lcur[i] = c ? atomicAdd(&bpos[i * 16], c) : 0;
    }
    __syncthreads();
    for (int i = s + t; i < en; i += 256) {
        int d = dst[i];
        int p = atomicAdd(&lcur[d >> BSH], 1);
        pool[p] = (unsigned)src[i] | ((unsigned)(d & 255) << 17);
    }
}

__global__ void nhist_k(const unsigned* __restrict__ pool, const int* __restrict__ boff,
                        int* __restrict__ cnt, int n) {
    __shared__ int lc[256];
    int b = blockIdx.x, t = threadIdx.x;
    lc[t] = 0;
    __syncthreads();
    int s = boff[b], e = boff[b + 1];
    for (int i = s + t; i < e; i += 256) atomicAdd(&lc[pool[i] >> 17], 1);
    __syncthreads();
    int nd = (b << BSH) + t;
    if (nd < n) cnt[nd] = lc[t];
}

__global__ void scan_partial_k(const int* __restrict__ cnt, int* __restrict__ part, int n) {
    __shared__ int lds[256];
    int base = blockIdx.x * 1024;
    int t = threadIdx.x;
    int s = 0;
    for (int j = 0; j < 4; j++) {
        int idx = base + t * 4 + j;
        if (idx < n) s += cnt[idx];
    }
    lds[t] = s;
    __syncthreads();
    for (int off = 128; off > 0; off >>= 1) {
        if (t < off) lds[t] += lds[t + off];
        __syncthreads();
    }
    if (t == 0) part[blockIdx.x] = lds[0];
}

__global__ void scan_root_k(int* part, int nb) {
    if (threadIdx.x == 0 && blockIdx.x == 0) {
        int run = 0;
        for (int i = 0; i < nb; i++) { int v = part[i]; part[i] = run; run += v; }
    }
}

__global__ void scan_final_k(const int* __restrict__ cnt, const int* __restrict__ part,
                             int* __restrict__ row_ptr, int n) {
    __shared__ int lds[256];
    int base = blockIdx.x * 1024;
    int t = threadIdx.x;
    int v[4];
    int s = 0;
    for (int j = 0; j < 4; j++) {
        int idx = base + t * 4 + j;
        v[j] = (idx < n) ? cnt[idx] : 0;
        s += v[j];
    }
    lds[t] = s;
    __syncthreads();
    for (int off = 1; off < 256; off <<= 1) {
        int xv = (t >= off) ? lds[t - off] : 0;
        __syncthreads();
        lds[t] += xv;
        __syncthreads();
    }
    int ex = (t > 0 ? lds[t - 1] : 0) + part[blockIdx.x];
    for (int j = 0; j < 4; j++) {
        int idx = base + t * 4 + j;
        if (idx < n) {
            row_ptr[idx] = ex;
            if (idx == n - 1) row_ptr[n] = ex + v[j];
            ex += v[j];
        }
    }
}

__global__ void cfill_k(const unsigned* __restrict__ pool, const int* __restrict__ boff,
                        const int* __restrict__ rp, int* __restrict__ col, int n) {
    __shared__ int lpos[256];
    int b = blockIdx.x, t = threadIdx.x;
    int nd = (b << BSH) + t;
    lpos[t] = (nd < n) ? rp[nd] : 0;
    __syncthreads();
    int s = boff[b], e = boff[b + 1];
    for (int i = s + t; i < e; i += 256) {
        unsigned pk = pool[i];
        int slot = atomicAdd(&lpos[pk >> 17], 1);
        col[slot] = (int)(pk & 0x1FFFFu);
    }
}

// -------------------------------------------------------------- converters
struct ConvDesc { const float* w; bf16_t* o; int kin; int kpad; };
struct ConvArgs { ConvDesc d[8]; };

__global__ void conv_w_k(ConvArgs args) {
    ConvDesc d = args.d[blockIdx.y];
    int i = blockIdx.x * 256 + threadIdx.x;
    int tot = 128 * d.kpad;
    if (i >= tot) return;
    int n = i / d.kpad, k = i - n * d.kpad;
    float v = (k < d.kin) ? d.w[(size_t)k * 128 + n] : 0.f;
    d.o[i] = (bf16_t)v;
}

__global__ void conv_x_k(const float* __restrict__ x, bf16_t* __restrict__ xb, int n) {
    int i = blockIdx.x * 256 + threadIdx.x;
    if (i >= n * 64) return;
    int node = i >> 6, k = i & 63;
    xb[i] = (k < D_IN) ? (bf16_t)x[node * D_IN + k] : (bf16_t)0.f;
}

// ------------------------------------------------------------- aggregation
// Wide-gather: one wave per node. D=64ch: 8 lanes x 16B per row, 8 neighbors
// in flight per VMEM instruction. D=128ch: 16 lanes x 16B, 4 neighbors.
__global__ void agg_bf64_k(const bf16_t* __restrict__ feat, const int* __restrict__ rp,
                           const int* __restrict__ col, bf16_t* __restrict__ mean, int n) {
    int wid = (blockIdx.x * blockDim.x + threadIdx.x) >> 6;
    int lane = threadIdx.x & 63;
    if (wid >= n) return;
    int start = rp[wid], end = rp[wid + 1];
    int lc = lane & 7;        // chunk within row (8 x 8 bf16 = 64 ch)
    int g = lane >> 3;        // neighbor group 0..7
    float acc[8];
#pragma unroll
    for (int k = 0; k < 8; k++) acc[k] = 0.f;
    for (int e = start + g; e < end; e += 8) {
        int s0 = col[e];
        bf16x8 v = *(const bf16x8*)(feat + (size_t)s0 * 64 + lc * 8);
#pragma unroll
        for (int k = 0; k < 8; k++) acc[k] += (float)v[k];
    }
#pragma unroll
    for (int off = 8; off < 64; off <<= 1) {
#pragma unroll
        for (int k = 0; k < 8; k++) acc[k] += __shfl_xor(acc[k], off);
    }
    int c = end - start;
    float invc = 1.f / (float)(c > 0 ? c : 1);
    if (lane < 8) {
        bf16x8 o;
#pragma unroll
        for (int k = 0; k < 8; k++) o[k] = (bf16_t)(acc[k] * invc);
        *(bf16x8*)(mean + (size_t)wid * 64 + lc * 8) = o;
    }
}

__global__ void agg_bf128_k(const bf16_t* __restrict__ feat, const int* __restrict__ rp,
                            const int* __restrict__ col, bf16_t* __restrict__ mean, int n) {
    int wid = (blockIdx.x * blockDim.x + threadIdx.x) >> 6;
    int lane = threadIdx.x & 63;
    if (wid >= n) return;
    int start = rp[wid], end = rp[wid + 1];
    int lc = lane & 15;       // chunk within row (16 x 8 bf16 = 128 ch)
    int g = lane >> 4;        // neighbor group 0..3
    float acc[8];
#pragma unroll
    for (int k = 0; k < 8; k++) acc[k] = 0.f;
    for (int e = start + g; e < end; e += 4) {
        int s0 = col[e];
        bf16x8 v = *(const bf16x8*)(feat + (size_t)s0 * 128 + lc * 8);
#pragma unroll
        for (int k = 0; k < 8; k++) acc[k] += (float)v[k];
    }
#pragma unroll
    for (int off = 16; off < 64; off <<= 1) {
#pragma unroll
        for (int k = 0; k < 8; k++) acc[k] += __shfl_xor(acc[k], off);
    }
    int c = end - start;
    float invc = 1.f / (float)(c > 0 ? c : 1);
    if (lane < 16) {
        bf16x8 o;
#pragma unroll
        for (int k = 0; k < 8; k++) o[k] = (bf16_t)(acc[k] * invc);
        *(bf16x8*)(mean + (size_t)wid * 128 + lc * 8) = o;
    }
}

// ------------------------------------------------- fused SAGE linear (MFMA)
// Dual (layers 2,3): out = A@WlT^T + B@WrT^T + bias, LN partials.
template <int KPAD, bool DUAL, bool ACC>
__global__ __launch_bounds__(256) void mfma_gemm_k(
    const bf16_t* __restrict__ A, const bf16_t* __restrict__ B,
    const bf16_t* __restrict__ WlT, const bf16_t* __restrict__ WrT,
    const float* __restrict__ bias,
    bf16_t* __restrict__ out, float2* __restrict__ partials, int M) {
    constexpr int KC = KPAD / 32;
    constexpr int WELE = 8 * KC * 64 * 8;
    __shared__ bf16_t lwl[WELE];
    __shared__ bf16_t lwr[DUAL ? WELE : 8];

    const int tid = threadIdx.x;
    for (int ch = tid; ch < 8 * KC * 64; ch += 256) {
        int nt = ch / (KC * 64);
        int rem = ch - nt * (KC * 64);
        int c = rem >> 6;
        int ln = rem & 63;
        int m = ln & 15, q = ln >> 4;
        size_t srcoff = (size_t)(nt * 16 + m) * KPAD + c * 32 + q * 8;
        *(bf16x8*)&lwl[ch * 8] = *(const bf16x8*)(WlT + srcoff);
        if (DUAL) *(bf16x8*)&lwr[ch * 8] = *(const bf16x8*)(WrT + srcoff);
    }
    __syncthreads();

    const int wid = blockIdx.x * 4 + (tid >> 6);
    const int lane = tid & 63;
    const int row0 = wid * 32;
    if (row0 >= M) return;
    const int m = lane & 15;
    const int q = lane >> 4;

    bf16x8 af[2][KC], bfr[DUAL ? 2 : 1][DUAL ? KC : 1];
#pragma unroll
    for (int s = 0; s < 2; s++) {
        const bf16_t* ar = A + (size_t)(row0 + s * 16 + m) * KPAD + q * 8;
#pragma unroll
        for (int c = 0; c < KC; c++) af[s][c] = *(const bf16x8*)(ar + c * 32);
        if (DUAL) {
            const bf16_t* br = B + (size_t)(row0 + s * 16 + m) * KPAD + q * 8;
#pragma unroll
            for (int c = 0; c < KC; c++) bfr[s][c] = *(const bf16x8*)(br + c * 32);
        }
    }

    float lsum = 0.f, lsum2 = 0.f;
#pragma unroll
    for (int nt = 0; nt < 8; nt++) {
        f32x4_t acc0 = {0.f, 0.f, 0.f, 0.f};
        f32x4_t acc1 = {0.f, 0.f, 0.f, 0.f};
#pragma unroll
        for (int c = 0; c < KC; c++) {
            bf16x8 w = *(const bf16x8*)&lwl[((nt * KC + c) * 64 + lane) * 8];
            acc0 = __builtin_amdgcn_mfma_f32_16x16x32_bf16(af[0][c], w, acc0, 0, 0, 0);
            acc1 = __builtin_amdgcn_mfma_f32_16x16x32_bf16(af[1][c], w, acc1, 0, 0, 0);
        }
        if (DUAL) {
#pragma unroll
            for (int c = 0; c < KC; c++) {
                bf16x8 w = *(const bf16x8*)&lwr[((nt * KC + c) * 64 + lane) * 8];
                acc0 = __builtin_amdgcn_mfma_f32_16x16x32_bf16(bfr[0][c], w, acc0, 0, 0, 0);
                acc1 = __builtin_amdgcn_mfma_f32_16x16x32_bf16(bfr[1][c], w, acc1, 0, 0, 0);
            }
        }
        float bv = bias ? bias[nt * 16 + m] : 0.f;
#pragma unroll
        for (int s = 0; s < 2; s++) {
            f32x4_t* ap = (s == 0) ? &acc0 : &acc1;
#pragma unroll
            for (int r = 0; r < 4; r++) {
                int row = row0 + s * 16 + q * 4 + r;
                if (row < M) {
                    float o = (*ap)[r] + bv;
                    out[(size_t)row * 128 + nt * 16 + m] = (bf16_t)o;
                    if (ACC) { lsum += o; lsum2 += o * o; }
                }
            }
        }
    }
    if (ACC) {
        for (int off = 32; off > 0; off >>= 1) {
            lsum += __shfl_down(lsum, off);
            lsum2 += __shfl_down(lsum2, off);
        }
        if (lane == 0) partials[wid] = make_float2(lsum, lsum2);
    }
}

// Layer-1 triple: PRE = mean@Wl1 + xb@Wr1 + b1 (LN partials),
// C1 = xb@Ws1, C2 = xb@Ws2. KPAD=64. 4 weights in 64KB LDS.
__global__ __launch_bounds__(256) void mfma_gemm3_k(
    const bf16_t* __restrict__ A, const bf16_t* __restrict__ B,
    const bf16_t* __restrict__ WlT, const bf16_t* __restrict__ WrT,
    const bf16_t* __restrict__ Ws1T, const bf16_t* __restrict__ Ws2T,
    const float* __restrict__ bias,
    bf16_t* __restrict__ outP, bf16_t* __restrict__ outC1, bf16_t* __restrict__ outC2,
    float2* __restrict__ partials, int M) {
    constexpr int KC = 2;
    constexpr int WELE = 8 * KC * 64 * 8;  // 16KB each
    __shared__ bf16_t lwl[WELE];
    __shared__ bf16_t lwr[WELE];
    __shared__ bf16_t ls1[WELE];
    __shared__ bf16_t ls2[WELE];

    const int tid = threadIdx.x;
    for (int ch = tid; ch < 8 * KC * 64; ch += 256) {
        int nt = ch / (KC * 64);
        int rem = ch - nt * (KC * 64);
        int c = rem >> 6;
        int ln = rem & 63;
        int m = ln & 15, q = ln >> 4;
        size_t srcoff = (size_t)(nt * 16 + m) * 64 + c * 32 + q * 8;
        *(bf16x8*)&lwl[ch * 8] = *(const bf16x8*)(WlT + srcoff);
        *(bf16x8*)&lwr[ch * 8] = *(const bf16x8*)(WrT + srcoff);
        *(bf16x8*)&ls1[ch * 8] = *(const bf16x8*)(Ws1T + srcoff);
        *(bf16x8*)&ls2[ch * 8] = *(const bf16x8*)(Ws2T + srcoff);
    }
    __syncthreads();

    const int wid = blockIdx.x * 4 + (tid >> 6);
    const int lane = tid & 63;
    const int row0 = wid * 32;
    if (row0 >= M) return;
    const int m = lane & 15;
    const int q = lane >> 4;

    bf16x8 af[2][KC], bfr[2][KC];
#pragma unroll
    for (int s = 0; s < 2; s++) {
        const bf16_t* ar = A + (size_t)(row0 + s * 16 + m) * 64 + q * 8;
        const bf16_t* br = B + (size_t)(row0 + s * 16 + m) * 64 + q * 8;
#pragma unroll
        for (int c = 0; c < KC; c++) {
            af[s][c] = *(const bf16x8*)(ar + c * 32);
            bfr[s][c] = *(const bf16x8*)(br + c * 32);
        }
    }

    float lsum = 0.f, lsum2 = 0.f;
#pragma unroll
    for (int nt = 0; nt < 8; nt++) {
        f32x4_t aP0 = {0.f, 0.f, 0.f, 0.f}, aP1 = {0.f, 0.f, 0.f, 0.f};
        f32x4_t a10 = {0.f, 0.f, 0.f, 0.f}, a11 = {0.f, 0.f, 0.f, 0.f};
        f32x4_t a20 = {0.f, 0.f, 0.f, 0.f}, a21 = {0.f, 0.f, 0.f, 0.f};
#pragma unroll
        for (int c = 0; c < KC; c++) {
            int wi = ((nt * KC + c) * 64 + lane) * 8;
            bf16x8 wl = *(const bf16x8*)&lwl[wi];
            bf16x8 wr = *(const bf16x8*)&lwr[wi];
            bf16x8 w1 = *(const bf16x8*)&ls1[wi];
            bf16x8 w2 = *(const bf16x8*)&ls2[wi];
            aP0 = __builtin_amdgcn_mfma_f32_16x16x32_bf16(af[0][c], wl, aP0, 0, 0, 0);
            aP1 = __builtin_amdgcn_mfma_f32_16x16x32_bf16(af[1][c], wl, aP1, 0, 0, 0);
            aP0 = __builtin_amdgcn_mfma_f32_16x16x32_bf16(bfr[0][c], wr, aP0, 0, 0, 0);
            aP1 = __builtin_amdgcn_mfma_f32_16x16x32_bf16(bfr[1][c], wr, aP1, 0, 0, 0);
            a10 = __builtin_amdgcn_mfma_f32_16x16x32_bf16(bfr[0][c], w1, a10, 0, 0, 0);
            a11 = __builtin_amdgcn_mfma_f32_16x16x32_bf16(bfr[1][c], w1, a11, 0, 0, 0);
            a20 = __builtin_amdgcn_mfma_f32_16x16x32_bf16(bfr[0][c], w2, a20, 0, 0, 0);
            a21 = __builtin_amdgcn_mfma_f32_16x16x32_bf16(bfr[1][c], w2, a21, 0, 0, 0);
        }
        float bv = bias[nt * 16 + m];
#pragma unroll
        for (int s = 0; s < 2; s++) {
            f32x4_t* pP = (s == 0) ? &aP0 : &aP1;
            f32x4_t* p1 = (s == 0) ? &a10 : &a11;
            f32x4_t* p2 = (s == 0) ? &a20 : &a21;
#pragma unroll
            for (int r = 0; r < 4; r++) {
                int row = row0 + s * 16 + q * 4 + r;
                if (row < M) {
                    float o = (*pP)[r] + bv;
                    size_t oi = (size_t)row * 128 + nt * 16 + m;
                    outP[oi] = (bf16_t)o;
                    outC1[oi] = (bf16_t)(*p1)[r];
                    outC2[oi] = (bf16_t)(*p2)[r];
                    lsum += o; lsum2 += o * o;
                }
            }
        }
    }
    for (int off = 32; off > 0; off >>= 1) {
        lsum += __shfl_down(lsum, off);
        lsum2 += __shfl_down(lsum2, off);
    }
    if (lane == 0) partials[wid] = make_float2(lsum, lsum2);
}

__global__ void reduce_partials_k(const float2* __restrict__ p, int n,
                                  double* __restrict__ outp) {
    __shared__ double s1[256], s2[256];
    int t = threadIdx.x;
    double a = 0.0, b = 0.0;
    for (int i = t; i < n; i += 256) { a += (double)p[i].x; b += (double)p[i].y; }
    s1[t] = a; s2[t] = b;
    __syncthreads();
    for (int off = 128; off > 0; off >>= 1) {
        if (t < off) { s1[t] += s1[t + off]; s2[t] += s2[t + off]; }
        __syncthreads();
    }
    if (t == 0) { outp[0] = s1[0]; outp[1] = s2[0]; }
}

// --------------------------------------------- LN (graph mode) + PReLU (+skip)
template <int MODE>
__global__ void ln_prelu_k(const bf16_t* __restrict__ pre, const bf16_t* __restrict__ h1in,
                           const bf16_t* __restrict__ s,
                           const float* __restrict__ lnw, const float* __restrict__ lnb,
                           const float* __restrict__ a_ptr, const double* __restrict__ acc,
                           void* __restrict__ out0v, void* __restrict__ out1v, int total) {
    int i = blockIdx.x * blockDim.x + threadIdx.x;
    if (i * 4 >= total) return;
    double cinv = 1.0 / (double)total;
    double mm = acc[0] * cinv;
    double var = acc[1] * cinv - mm * mm;
    float stdv = (float)sqrt(var > 0.0 ? var : 0.0);
    float scale = 1.0f / (stdv + LN_EPS);
    float mf = (float)mm;
    float a = a_ptr[0];
    int c4 = i & 31;
    float4 w = ((const float4*)lnw)[c4];
    float4 b = ((const float4*)lnb)[c4];
    bf16x4 p4 = ((const bf16x4*)pre)[i];
    float4 h;
    h.x = ((float)p4.x - mf) * scale * w.x + b.x;
    h.y = ((float)p4.y - mf) * scale * w.y + b.y;
    h.z = ((float)p4.z - mf) * scale * w.z + b.z;
    h.w = ((float)p4.w - mf) * scale * w.w + b.w;
    h.x = h.x >= 0.f ? h.x : a * h.x;
    h.y = h.y >= 0.f ? h.y : a * h.y;
    h.z = h.z >= 0.f ? h.z : a * h.z;
    h.w = h.w >= 0.f ? h.w : a * h.w;
    if (MODE == 1) {
        bf16x4 hb;
        hb.x = (bf16_t)h.x; hb.y = (bf16_t)h.y; hb.z = (bf16_t)h.z; hb.w = (bf16_t)h.w;
        ((bf16x4*)out0v)[i] = hb;
        bf16x4 sv = ((const bf16x4*)s)[i];
        bf16x4 tb;
        tb.x = (bf16_t)(h.x + (float)sv.x); tb.y = (bf16_t)(h.y + (float)sv.y);
        tb.z = (bf16_t)(h.z + (float)sv.z); tb.w = (bf16_t)(h.w + (float)sv.w);
        ((bf16x4*)out1v)[i] = tb;
    } else if (MODE == 2) {
        bf16x4 hv = ((const bf16x4*)h1in)[i];
        bf16x4 sv = ((const bf16x4*)s)[i];
        bf16x4 tb;
        tb.x = (bf16_t)((float)hv.x + h.x + (float)sv.x);
        tb.y = (bf16_t)((float)hv.y + h.y + (float)sv.y);
        tb.z = (bf16_t)((float)hv.z + h.z + (float)sv.z);
        tb.w = (bf16_t)((float)hv.w + h.w + (float)sv.w);
        ((bf16x4*)out0v)[i] = tb;
    } else {
        ((float4*)out0v)[i] = h;
    }
}

// ------------------------------------------------------------------ launch
extern "C" void kernel_launch(void* const* d_in, const int* in_sizes, int n_in,
                              void* d_out, int out_size, void* d_ws, size_t ws_size,
                              hipStream_t stream) {
    const float* x    = (const float*)d_in[0];
    const int*   esrc = (const int*)d_in[1];
    const int*   edst = (const int*)d_in[2];
    const float* Wl1  = (const float*)d_in[3];
    const float* Wr1  = (const float*)d_in[4];
    const float* b1   = (const float*)d_in[5];
    const float* Wl2  = (const float*)d_in[6];
    const float* Wr2  = (const float*)d_in[7];
    const float* b2   = (const float*)d_in[8];
    const float* Wl3  = (const float*)d_in[9];
    const float* Wr3  = (const float*)d_in[10];
    const float* b3   = (const float*)d_in[11];
    const float* Ws1  = (const float*)d_in[12];
    const float* Ws2  = (const float*)d_in[13];
    const float* lnw1 = (const float*)d_in[14];
    const float* lnb1 = (const float*)d_in[15];
    const float* lnw2 = (const float*)d_in[16];
    const float* lnb2 = (const float*)d_in[17];
    const float* lnw3 = (const float*)d_in[18];
    const float* lnb3 = (const float*)d_in[19];
    const float* a1   = (const float*)d_in[20];
    const float* a2   = (const float*)d_in[21];
    const float* a3   = (const float*)d_in[22];

    const int N = in_sizes[0] / D_IN;
    const int E = in_sizes[1];
    const int NB = (N + 255) >> BSH;

    char* ws = (char*)d_ws;
    size_t off = 0;
    auto alloc = [&](size_t bytes) -> void* {
        void* p = ws + off;
        off += (bytes + 255) & ~(size_t)255;
        return p;
    };
    bf16_t* xb   = (bf16_t*)alloc((size_t)N * 64 * 2);
    bf16_t* mean = (bf16_t*)alloc((size_t)N * 128 * 2);
    bf16_t* PRE  = (bf16_t*)alloc((size_t)N * 128 * 2);
    bf16_t* C1   = (bf16_t*)alloc((size_t)N * 128 * 2);
    bf16_t* C2   = (bf16_t*)alloc((size_t)N * 128 * 2);
    bf16_t* h1b  = (bf16_t*)alloc((size_t)N * 128 * 2);
    bf16_t* TB   = (bf16_t*)alloc((size_t)N * 128 * 2);
    bf16_t* WT   = (bf16_t*)alloc((size_t)(4 * 128 * 64 + 4 * 128 * 128) * 2);
    int* cnt  = (int*)alloc((size_t)N * 4);
    int* rp   = (int*)alloc((size_t)(N + 1) * 4);
    int* col  = (int*)alloc((size_t)E * 4);
    int* part = (int*)alloc(512);
    int* bcnt = (int*)alloc((size_t)MAXB * 16 * 4);
    int* boff = (int*)alloc((size_t)(MAXB + 1) * 4);
    int* bpos = (int*)alloc((size_t)MAXB * 16 * 4);
    unsigned* pool = (unsigned*)alloc((size_t)E * 4);
    double* lnacc = (double*)alloc(6 * 8);
    const int tiles = (N + 31) / 32;
    float2* partials = (float2*)alloc((size_t)tiles * 8);

    bf16_t* Wl1T = WT;
    bf16_t* Wr1T = Wl1T + 128 * 64;
    bf16_t* Ws1T = Wr1T + 128 * 64;
    bf16_t* Ws2T = Ws1T + 128 * 64;
    bf16_t* Wl2T = Ws2T + 128 * 64;
    bf16_t* Wr2T = Wl2T + 128 * 128;
    bf16_t* Wl3T = Wr2T + 128 * 128;
    bf16_t* Wr3T = Wl3T + 128 * 128;

    hipMemsetAsync(bcnt, 0, (size_t)MAXB * 16 * 4, stream);

    // --- bucketed CSR build
    const int NBS_n = (N + 1023) / 1024;
    bucket_hist_k<<<256, 256, 0, stream>>>(edst, bcnt, E, NB);
    bscan_k<<<1, MAXB, 0, stream>>>(bcnt, boff, bpos, NB, E);
    scatter_k<<<256, 256, 0, stream>>>(esrc, edst, bpos, pool, E, NB);
    nhist_k<<<NB, 256, 0, stream>>>(pool, boff, cnt, N);
    scan_partial_k<<<NBS_n, 256, 0, stream>>>(cnt, part, N);
    scan_root_k<<<1, 64, 0, stream>>>(part, NBS_n);
    scan_final_k<<<NBS_n, 256, 0, stream>>>(cnt, part, rp, N);
    cfill_k<<<NB, 256, 0, stream>>>(pool, boff, rp, col, N);

    // --- weight/feature conversion
    ConvArgs ca;
    ca.d[0] = {Wl1, Wl1T, 50, 64};
    ca.d[1] = {Wr1, Wr1T, 50, 64};
    ca.d[2] = {Ws1, Ws1T, 50, 64};
    ca.d[3] = {Ws2, Ws2T, 50, 64};
    ca.d[4] = {Wl2, Wl2T, 128, 128};
    ca.d[5] = {Wr2, Wr2T, 128, 128};
    ca.d[6] = {Wl3, Wl3T, 128, 128};
    ca.d[7] = {Wr3, Wr3T, 128, 128};
    conv_w_k<<<dim3(64, 8), 256, 0, stream>>>(ca);
    conv_x_k<<<(N * 64 + 255) / 256, 256, 0, stream>>>(x, xb, N);

    const int aggBlocks = ((N * 64) + 255) / 256;
    const int gemmBlocks = (tiles + 3) / 4;
    const int lnBlocks = (N * 128 / 4 + 255) / 256;
    const int total = N * 128;

    // ---- layer 1 (triple-fused GEMM: PRE, C1=x@Ws1, C2=x@Ws2)
    agg_bf64_k<<<aggBlocks, 256, 0, stream>>>(xb, rp, col, mean, N);
    mfma_gemm3_k<<<gemmBlocks, 256, 0, stream>>>(
        mean, xb, Wl1T, Wr1T, Ws1T, Ws2T, b1, PRE, C1, C2, partials, N);
    reduce_partials_k<<<1, 256, 0, stream>>>(partials, tiles, lnacc + 0);
    ln_prelu_k<1><<<lnBlocks, 256, 0, stream>>>(
        PRE, nullptr, C1, lnw1, lnb1, a1, lnacc + 0, h1b, TB, total);

    // ---- layer 2
    agg_bf128_k<<<aggBlocks, 256, 0, stream>>>(TB, rp, col, mean, N);
    mfma_gemm_k<128, true, true><<<gemmBlocks, 256, 0, stream>>>(
        mean, TB, Wl2T, Wr2T, b2, PRE, partials, N);
    reduce_partials_k<<<1, 256, 0, stream>>>(partials, tiles, lnacc + 2);
    ln_prelu_k<2><<<lnBlocks, 256, 0, stream>>>(
        PRE, h1b, C2, lnw2, lnb2, a2, lnacc + 2, TB, nullptr, total);

    // ---- layer 3
    agg_bf128_k<<<aggBlocks, 256, 0, stream>>>(TB, rp, col, mean, N);
    mfma_gemm_k<128, true, true><<<gemmBlocks, 256, 0, stream>>>(
        mean, TB, Wl3T, Wr3T, b3, PRE, partials, N);
    reduce_partials_k<<<1, 256, 0, stream>>>(partials, tiles, lnacc + 4);
    ln_prelu_k<3><<<lnBlocks, 256, 0, stream>>>(
        PRE, nullptr, nullptr, lnw3, lnb3, a3, lnacc + 4, d_out, nullptr, total);
}

// Round 7
// 552.916 us; speedup vs baseline: 1.8838x; 1.0485x over previous
//
#include <hip/hip_runtime.h>

#define D_IN 50
#define LN_EPS 1e-5f
#define BSH 8           // 256 nodes per bucket
#define MAXB 512        // max buckets (N <= 131072)

typedef __bf16 bf16_t;
typedef bf16_t bf16x8 __attribute__((ext_vector_type(8)));
typedef bf16_t bf16x4 __attribute__((ext_vector_type(4)));
typedef bf16_t bf16x2 __attribute__((ext_vector_type(2)));
typedef float f32x4_t __attribute__((ext_vector_type(4)));

// accumulate 4 u32 (8 bf16) into lo/hi float banks; bf16->f32 is a shift
#define ACC8(r, L, H)                                                        \
    {                                                                        \
        L[0] += __uint_as_float((r).x << 16);                                \
        H[0] += __uint_as_float((r).x & 0xffff0000u);                        \
        L[1] += __uint_as_float((r).y << 16);                                \
        H[1] += __uint_as_float((r).y & 0xffff0000u);                        \
        L[2] += __uint_as_float((r).z << 16);                                \
        H[2] += __uint_as_float((r).z & 0xffff0000u);                        \
        L[3] += __uint_as_float((r).w << 16);                                \
        H[3] += __uint_as_float((r).w & 0xffff0000u);                        \
    }

// ---------------------------------------------------------------- CSR build
__global__ void bucket_hist_k(const int* __restrict__ dst, int* __restrict__ bcnt,
                              int e, int nb) {
    __shared__ int lh[MAXB];
    int t = threadIdx.x;
    for (int i = t; i < nb; i += 256) lh[i] = 0;
    __syncthreads();
    for (int i = blockIdx.x * 256 + t; i < e; i += gridDim.x * 256)
        atomicAdd(&lh[dst[i] >> BSH], 1);
    __syncthreads();
    for (int i = t; i < nb; i += 256) {
        int c = lh[i];
        if (c) atomicAdd(&bcnt[i * 16], c);
    }
}

__global__ void bscan_k(const int* __restrict__ bcnt, int* __restrict__ boff,
                        int* __restrict__ bpos, int nb, int e) {
    __shared__ int l[MAXB];
    int t = threadIdx.x;
    l[t] = (t < nb) ? bcnt[t * 16] : 0;
    __syncthreads();
    for (int off = 1; off < MAXB; off <<= 1) {
        int v = (t >= off) ? l[t - off] : 0;
        __syncthreads();
        l[t] += v;
        __syncthreads();
    }
    int excl = (t > 0) ? l[t - 1] : 0;
    if (t < nb) { boff[t] = excl; bpos[t * 16] = excl; }
    if (t == 0) boff[nb] = e;
}

__global__ void scatter_k(const int* __restrict__ src, const int* __restrict__ dst,
                          int* __restrict__ bpos, unsigned* __restrict__ pool,
                          int e, int nb) {
    __shared__ int lh[MAXB];
    __shared__ int lcur[MAXB];
    int t = threadIdx.x;
    for (int i = t; i < nb; i += 256) lh[i] = 0;
    __syncthreads();
    int chunk = (e + gridDim.x - 1) / gridDim.x;
    int s = blockIdx.x * chunk;
    int en = min(e, s + chunk);
    for (int i = s + t; i < en; i += 256)
        atomicAdd(&lh[dst[i] >> BSH], 1);
    __syncthreads();
    for (int i = t; i < nb; i += 256) {
        int c = lh[i];
        lcur[i] = c ? atomicAdd(&bpos[i * 16], c) : 0;
    }
    __syncthreads();
    for (int i = s + t; i < en; i += 256) {
        int d = dst[i];
        int p = atomicAdd(&lcur[d >> BSH], 1);
        pool[p] = (unsigned)src[i] | ((unsigned)(d & 255) << 17);
    }
}

__global__ void nhist_k(const unsigned* __restrict__ pool, const int* __restrict__ boff,
                        int* __restrict__ cnt, int n) {
    __shared__ int lc[256];
    int b = blockIdx.x, t = threadIdx.x;
    lc[t] = 0;
    __syncthreads();
    int s = boff[b], e = boff[b + 1];
    for (int i = s + t; i < e; i += 256) atomicAdd(&lc[pool[i] >> 17], 1);
    __syncthreads();
    int nd = (b << BSH) + t;
    if (nd < n) cnt[nd] = lc[t];
}

__global__ void scan_partial_k(const int* __restrict__ cnt, int* __restrict__ part, int n) {
    __shared__ int lds[256];
    int base = blockIdx.x * 1024;
    int t = threadIdx.x;
    int s = 0;
    for (int j = 0; j < 4; j++) {
        int idx = base + t * 4 + j;
        if (idx < n) s += cnt[idx];
    }
    lds[t] = s;
    __syncthreads();
    for (int off = 128; off > 0; off >>= 1) {
        if (t < off) lds[t] += lds[t + off];
        __syncthreads();
    }
    if (t == 0) part[blockIdx.x] = lds[0];
}

// parallel exclusive scan over <=256 partials (was a serial 1-thread loop)
__global__ void scan_root_k(int* part, int nb) {
    __shared__ int l[256];
    int t = threadIdx.x;
    int v = (t < nb) ? part[t] : 0;
    l[t] = v;
    __syncthreads();
    for (int off = 1; off < 256; off <<= 1) {
        int x = (t >= off) ? l[t - off] : 0;
        __syncthreads();
        l[t] += x;
        __syncthreads();
    }
    if (t < nb) part[t] = l[t] - v;
}

__global__ void scan_final_k(const int* __restrict__ cnt, const int* __restrict__ part,
                             int* __restrict__ row_ptr, int n) {
    __shared__ int lds[256];
    int base = blockIdx.x * 1024;
    int t = threadIdx.x;
    int v[4];
    int s = 0;
    for (int j = 0; j < 4; j++) {
        int idx = base + t * 4 + j;
        v[j] = (idx < n) ? cnt[idx] : 0;
        s += v[j];
    }
    lds[t] = s;
    __syncthreads();
    for (int off = 1; off < 256; off <<= 1) {
        int xv = (t >= off) ? lds[t - off] : 0;
        __syncthreads();
        lds[t] += xv;
        __syncthreads();
    }
    int ex = (t > 0 ? lds[t - 1] : 0) + part[blockIdx.x];
    for (int j = 0; j < 4; j++) {
        int idx = base + t * 4 + j;
        if (idx < n) {
            row_ptr[idx] = ex;
            if (idx == n - 1) row_ptr[n] = ex + v[j];
            ex += v[j];
        }
    }
}

__global__ void cfill_k(const unsigned* __restrict__ pool, const int* __restrict__ boff,
                        const int* __restrict__ rp, int* __restrict__ col, int n) {
    __shared__ int lpos[256];
    int b = blockIdx.x, t = threadIdx.x;
    int nd = (b << BSH) + t;
    lpos[t] = (nd < n) ? rp[nd] : 0;
    __syncthreads();
    int s = boff[b], e = boff[b + 1];
    for (int i = s + t; i < e; i += 256) {
        unsigned pk = pool[i];
        int slot = atomicAdd(&lpos[pk >> 17], 1);
        col[slot] = (int)(pk & 0x1FFFFu);
    }
}

// -------------------------------------------------------------- converters
struct ConvDesc { const float* w; bf16_t* o; int kin; int kpad; };
struct ConvArgs { ConvDesc d[8]; };

__global__ void conv_w_k(ConvArgs args) {
    ConvDesc d = args.d[blockIdx.y];
    int i = blockIdx.x * 256 + threadIdx.x;
    int tot = 128 * d.kpad;
    if (i >= tot) return;
    int n = i / d.kpad, k = i - n * d.kpad;
    float v = (k < d.kin) ? d.w[(size_t)k * 128 + n] : 0.f;
    d.o[i] = (bf16_t)v;
}

__global__ void conv_x_k(const float* __restrict__ x, bf16_t* __restrict__ xb, int n) {
    int i = blockIdx.x * 256 + threadIdx.x;
    if (i >= n * 64) return;
    int node = i >> 6, k = i & 63;
    xb[i] = (k < D_IN) ? (bf16_t)x[node * D_IN + k] : (bf16_t)0.f;
}

// ------------------------------------------------------------- aggregation
// Wide-gather + 2x unroll: one wave per node; 16B/lane row chunks; each lane
// keeps 2 loads in flight (separate accumulator banks) before consuming.
__global__ void agg_bf64_k(const bf16_t* __restrict__ feat, const int* __restrict__ rp,
                           const int* __restrict__ col, bf16_t* __restrict__ mean, int n) {
    int wid = (blockIdx.x * blockDim.x + threadIdx.x) >> 6;
    int lane = threadIdx.x & 63;
    if (wid >= n) return;
    int start = rp[wid], end = rp[wid + 1];
    int lc = lane & 7;        // chunk within row (8 x 8 bf16 = 64 ch)
    int g = lane >> 3;        // neighbor group 0..7
    float aL[4], aH[4], bL[4], bH[4];
#pragma unroll
    for (int k = 0; k < 4; k++) { aL[k] = aH[k] = bL[k] = bH[k] = 0.f; }
    int e = start + g;
    for (; e + 8 < end; e += 16) {
        uint4 r0 = *(const uint4*)(feat + (size_t)col[e] * 64 + lc * 8);
        uint4 r1 = *(const uint4*)(feat + (size_t)col[e + 8] * 64 + lc * 8);
        ACC8(r0, aL, aH);
        ACC8(r1, bL, bH);
    }
    for (; e < end; e += 8) {
        uint4 r0 = *(const uint4*)(feat + (size_t)col[e] * 64 + lc * 8);
        ACC8(r0, aL, aH);
    }
#pragma unroll
    for (int k = 0; k < 4; k++) { aL[k] += bL[k]; aH[k] += bH[k]; }
#pragma unroll
    for (int off = 8; off < 64; off <<= 1) {
#pragma unroll
        for (int k = 0; k < 4; k++) {
            aL[k] += __shfl_xor(aL[k], off);
            aH[k] += __shfl_xor(aH[k], off);
        }
    }
    int c = end - start;
    float invc = 1.f / (float)(c > 0 ? c : 1);
    if (lane < 8) {
        bf16x8 o;
#pragma unroll
        for (int k = 0; k < 4; k++) {
            o[2 * k] = (bf16_t)(aL[k] * invc);
            o[2 * k + 1] = (bf16_t)(aH[k] * invc);
        }
        *(bf16x8*)(mean + (size_t)wid * 64 + lc * 8) = o;
    }
}

__global__ void agg_bf128_k(const bf16_t* __restrict__ feat, const int* __restrict__ rp,
                            const int* __restrict__ col, bf16_t* __restrict__ mean, int n) {
    int wid = (blockIdx.x * blockDim.x + threadIdx.x) >> 6;
    int lane = threadIdx.x & 63;
    if (wid >= n) return;
    int start = rp[wid], end = rp[wid + 1];
    int lc = lane & 15;       // chunk within row (16 x 8 bf16 = 128 ch)
    int g = lane >> 4;        // neighbor group 0..3
    float aL[4], aH[4], bL[4], bH[4];
#pragma unroll
    for (int k = 0; k < 4; k++) { aL[k] = aH[k] = bL[k] = bH[k] = 0.f; }
    int e = start + g;
    for (; e + 4 < end; e += 8) {
        uint4 r0 = *(const uint4*)(feat + (size_t)col[e] * 128 + lc * 8);
        uint4 r1 = *(const uint4*)(feat + (size_t)col[e + 4] * 128 + lc * 8);
        ACC8(r0, aL, aH);
        ACC8(r1, bL, bH);
    }
    for (; e < end; e += 4) {
        uint4 r0 = *(const uint4*)(feat + (size_t)col[e] * 128 + lc * 8);
        ACC8(r0, aL, aH);
    }
#pragma unroll
    for (int k = 0; k < 4; k++) { aL[k] += bL[k]; aH[k] += bH[k]; }
#pragma unroll
    for (int off = 16; off < 64; off <<= 1) {
#pragma unroll
        for (int k = 0; k < 4; k++) {
            aL[k] += __shfl_xor(aL[k], off);
            aH[k] += __shfl_xor(aH[k], off);
        }
    }
    int c = end - start;
    float invc = 1.f / (float)(c > 0 ? c : 1);
    if (lane < 16) {
        bf16x8 o;
#pragma unroll
        for (int k = 0; k < 4; k++) {
            o[2 * k] = (bf16_t)(aL[k] * invc);
            o[2 * k + 1] = (bf16_t)(aH[k] * invc);
        }
        *(bf16x8*)(mean + (size_t)wid * 128 + lc * 8) = o;
    }
}

// ------------------------------------------------- fused SAGE linear (MFMA)
template <int KPAD, bool DUAL, bool ACC>
__global__ __launch_bounds__(256) void mfma_gemm_k(
    const bf16_t* __restrict__ A, const bf16_t* __restrict__ B,
    const bf16_t* __restrict__ WlT, const bf16_t* __restrict__ WrT,
    const float* __restrict__ bias,
    bf16_t* __restrict__ out, float2* __restrict__ partials, int M) {
    constexpr int KC = KPAD / 32;
    constexpr int WELE = 8 * KC * 64 * 8;
    __shared__ bf16_t lwl[WELE];
    __shared__ bf16_t lwr[DUAL ? WELE : 8];

    const int tid = threadIdx.x;
    for (int ch = tid; ch < 8 * KC * 64; ch += 256) {
        int nt = ch / (KC * 64);
        int rem = ch - nt * (KC * 64);
        int c = rem >> 6;
        int ln = rem & 63;
        int m = ln & 15, q = ln >> 4;
        size_t srcoff = (size_t)(nt * 16 + m) * KPAD + c * 32 + q * 8;
        *(bf16x8*)&lwl[ch * 8] = *(const bf16x8*)(WlT + srcoff);
        if (DUAL) *(bf16x8*)&lwr[ch * 8] = *(const bf16x8*)(WrT + srcoff);
    }
    __syncthreads();

    const int wid = blockIdx.x * 4 + (tid >> 6);
    const int lane = tid & 63;
    const int row0 = wid * 32;
    if (row0 >= M) return;
    const int m = lane & 15;
    const int q = lane >> 4;

    bf16x8 af[2][KC], bfr[DUAL ? 2 : 1][DUAL ? KC : 1];
#pragma unroll
    for (int s = 0; s < 2; s++) {
        const bf16_t* ar = A + (size_t)(row0 + s * 16 + m) * KPAD + q * 8;
#pragma unroll
        for (int c = 0; c < KC; c++) af[s][c] = *(const bf16x8*)(ar + c * 32);
        if (DUAL) {
            const bf16_t* br = B + (size_t)(row0 + s * 16 + m) * KPAD + q * 8;
#pragma unroll
            for (int c = 0; c < KC; c++) bfr[s][c] = *(const bf16x8*)(br + c * 32);
        }
    }

    float lsum = 0.f, lsum2 = 0.f;
#pragma unroll
    for (int nt = 0; nt < 8; nt++) {
        f32x4_t acc0 = {0.f, 0.f, 0.f, 0.f};
        f32x4_t acc1 = {0.f, 0.f, 0.f, 0.f};
#pragma unroll
        for (int c = 0; c < KC; c++) {
            bf16x8 w = *(const bf16x8*)&lwl[((nt * KC + c) * 64 + lane) * 8];
            acc0 = __builtin_amdgcn_mfma_f32_16x16x32_bf16(af[0][c], w, acc0, 0, 0, 0);
            acc1 = __builtin_amdgcn_mfma_f32_16x16x32_bf16(af[1][c], w, acc1, 0, 0, 0);
        }
        if (DUAL) {
#pragma unroll
            for (int c = 0; c < KC; c++) {
                bf16x8 w = *(const bf16x8*)&lwr[((nt * KC + c) * 64 + lane) * 8];
                acc0 = __builtin_amdgcn_mfma_f32_16x16x32_bf16(bfr[0][c], w, acc0, 0, 0, 0);
                acc1 = __builtin_amdgcn_mfma_f32_16x16x32_bf16(bfr[1][c], w, acc1, 0, 0, 0);
            }
        }
        float bv = bias ? bias[nt * 16 + m] : 0.f;
#pragma unroll
        for (int s = 0; s < 2; s++) {
            f32x4_t* ap = (s == 0) ? &acc0 : &acc1;
#pragma unroll
            for (int r = 0; r < 4; r++) {
                int row = row0 + s * 16 + q * 4 + r;
                if (row < M) {
                    float o = (*ap)[r] + bv;
                    out[(size_t)row * 128 + nt * 16 + m] = (bf16_t)o;
                    if (ACC) { lsum += o; lsum2 += o * o; }
                }
            }
        }
    }
    if (ACC) {
        for (int off = 32; off > 0; off >>= 1) {
            lsum += __shfl_down(lsum, off);
            lsum2 += __shfl_down(lsum2, off);
        }
        if (lane == 0) partials[wid] = make_float2(lsum, lsum2);
    }
}

// Layer-1 triple: PRE = mean@Wl1 + xb@Wr1 + b1 (LN partials),
// C1 = xb@Ws1, C2 = xb@Ws2. KPAD=64.
__global__ __launch_bounds__(256) void mfma_gemm3_k(
    const bf16_t* __restrict__ A, const bf16_t* __restrict__ B,
    const bf16_t* __restrict__ WlT, const bf16_t* __restrict__ WrT,
    const bf16_t* __restrict__ Ws1T, const bf16_t* __restrict__ Ws2T,
    const float* __restrict__ bias,
    bf16_t* __restrict__ outP, bf16_t* __restrict__ outC1, bf16_t* __restrict__ outC2,
    float2* __restrict__ partials, int M) {
    constexpr int KC = 2;
    constexpr int WELE = 8 * KC * 64 * 8;
    __shared__ bf16_t lwl[WELE];
    __shared__ bf16_t lwr[WELE];
    __shared__ bf16_t ls1[WELE];
    __shared__ bf16_t ls2[WELE];

    const int tid = threadIdx.x;
    for (int ch = tid; ch < 8 * KC * 64; ch += 256) {
        int nt = ch / (KC * 64);
        int rem = ch - nt * (KC * 64);
        int c = rem >> 6;
        int ln = rem & 63;
        int m = ln & 15, q = ln >> 4;
        size_t srcoff = (size_t)(nt * 16 + m) * 64 + c * 32 + q * 8;
        *(bf16x8*)&lwl[ch * 8] = *(const bf16x8*)(WlT + srcoff);
        *(bf16x8*)&lwr[ch * 8] = *(const bf16x8*)(WrT + srcoff);
        *(bf16x8*)&ls1[ch * 8] = *(const bf16x8*)(Ws1T + srcoff);
        *(bf16x8*)&ls2[ch * 8] = *(const bf16x8*)(Ws2T + srcoff);
    }
    __syncthreads();

    const int wid = blockIdx.x * 4 + (tid >> 6);
    const int lane = tid & 63;
    const int row0 = wid * 32;
    if (row0 >= M) return;
    const int m = lane & 15;
    const int q = lane >> 4;

    bf16x8 af[2][KC], bfr[2][KC];
#pragma unroll
    for (int s = 0; s < 2; s++) {
        const bf16_t* ar = A + (size_t)(row0 + s * 16 + m) * 64 + q * 8;
        const bf16_t* br = B + (size_t)(row0 + s * 16 + m) * 64 + q * 8;
#pragma unroll
        for (int c = 0; c < KC; c++) {
            af[s][c] = *(const bf16x8*)(ar + c * 32);
            bfr[s][c] = *(const bf16x8*)(br + c * 32);
        }
    }

    float lsum = 0.f, lsum2 = 0.f;
#pragma unroll
    for (int nt = 0; nt < 8; nt++) {
        f32x4_t aP0 = {0.f, 0.f, 0.f, 0.f}, aP1 = {0.f, 0.f, 0.f, 0.f};
        f32x4_t a10 = {0.f, 0.f, 0.f, 0.f}, a11 = {0.f, 0.f, 0.f, 0.f};
        f32x4_t a20 = {0.f, 0.f, 0.f, 0.f}, a21 = {0.f, 0.f, 0.f, 0.f};
#pragma unroll
        for (int c = 0; c < KC; c++) {
            int wi = ((nt * KC + c) * 64 + lane) * 8;
            bf16x8 wl = *(const bf16x8*)&lwl[wi];
            bf16x8 wr = *(const bf16x8*)&lwr[wi];
            bf16x8 w1 = *(const bf16x8*)&ls1[wi];
            bf16x8 w2 = *(const bf16x8*)&ls2[wi];
            aP0 = __builtin_amdgcn_mfma_f32_16x16x32_bf16(af[0][c], wl, aP0, 0, 0, 0);
            aP1 = __builtin_amdgcn_mfma_f32_16x16x32_bf16(af[1][c], wl, aP1, 0, 0, 0);
            aP0 = __builtin_amdgcn_mfma_f32_16x16x32_bf16(bfr[0][c], wr, aP0, 0, 0, 0);
            aP1 = __builtin_amdgcn_mfma_f32_16x16x32_bf16(bfr[1][c], wr, aP1, 0, 0, 0);
            a10 = __builtin_amdgcn_mfma_f32_16x16x32_bf16(bfr[0][c], w1, a10, 0, 0, 0);
            a11 = __builtin_amdgcn_mfma_f32_16x16x32_bf16(bfr[1][c], w1, a11, 0, 0, 0);
            a20 = __builtin_amdgcn_mfma_f32_16x16x32_bf16(bfr[0][c], w2, a20, 0, 0, 0);
            a21 = __builtin_amdgcn_mfma_f32_16x16x32_bf16(bfr[1][c], w2, a21, 0, 0, 0);
        }
        float bv = bias[nt * 16 + m];
#pragma unroll
        for (int s = 0; s < 2; s++) {
            f32x4_t* pP = (s == 0) ? &aP0 : &aP1;
            f32x4_t* p1 = (s == 0) ? &a10 : &a11;
            f32x4_t* p2 = (s == 0) ? &a20 : &a21;
#pragma unroll
            for (int r = 0; r < 4; r++) {
                int row = row0 + s * 16 + q * 4 + r;
                if (row < M) {
                    float o = (*pP)[r] + bv;
                    size_t oi = (size_t)row * 128 + nt * 16 + m;
                    outP[oi] = (bf16_t)o;
                    outC1[oi] = (bf16_t)(*p1)[r];
                    outC2[oi] = (bf16_t)(*p2)[r];
                    lsum += o; lsum2 += o * o;
                }
            }
        }
    }
    for (int off = 32; off > 0; off >>= 1) {
        lsum += __shfl_down(lsum, off);
        lsum2 += __shfl_down(lsum2, off);
    }
    if (lane == 0) partials[wid] = make_float2(lsum, lsum2);
}

__global__ void reduce_partials_k(const float2* __restrict__ p, int n,
                                  double* __restrict__ outp) {
    __shared__ double s1[256], s2[256];
    int t = threadIdx.x;
    double a = 0.0, b = 0.0;
    for (int i = t; i < n; i += 256) { a += (double)p[i].x; b += (double)p[i].y; }
    s1[t] = a; s2[t] = b;
    __syncthreads();
    for (int off = 128; off > 0; off >>= 1) {
        if (t < off) { s1[t] += s1[t + off]; s2[t] += s2[t + off]; }
        __syncthreads();
    }
    if (t == 0) { outp[0] = s1[0]; outp[1] = s2[0]; }
}

// --------------------------------------------- LN (graph mode) + PReLU (+skip)
template <int MODE>
__global__ void ln_prelu_k(const bf16_t* __restrict__ pre, const bf16_t* __restrict__ h1in,
                           const bf16_t* __restrict__ s,
                           const float* __restrict__ lnw, const float* __restrict__ lnb,
                           const float* __restrict__ a_ptr, const double* __restrict__ acc,
                           void* __restrict__ out0v, void* __restrict__ out1v, int total) {
    int i = blockIdx.x * blockDim.x + threadIdx.x;
    if (i * 4 >= total) return;
    double cinv = 1.0 / (double)total;
    double mm = acc[0] * cinv;
    double var = acc[1] * cinv - mm * mm;
    float stdv = (float)sqrt(var > 0.0 ? var : 0.0);
    float scale = 1.0f / (stdv + LN_EPS);
    float mf = (float)mm;
    float a = a_ptr[0];
    int c4 = i & 31;
    float4 w = ((const float4*)lnw)[c4];
    float4 b = ((const float4*)lnb)[c4];
    bf16x4 p4 = ((const bf16x4*)pre)[i];
    float4 h;
    h.x = ((float)p4.x - mf) * scale * w.x + b.x;
    h.y = ((float)p4.y - mf) * scale * w.y + b.y;
    h.z = ((float)p4.z - mf) * scale * w.z + b.z;
    h.w = ((float)p4.w - mf) * scale * w.w + b.w;
    h.x = h.x >= 0.f ? h.x : a * h.x;
    h.y = h.y >= 0.f ? h.y : a * h.y;
    h.z = h.z >= 0.f ? h.z : a * h.z;
    h.w = h.w >= 0.f ? h.w : a * h.w;
    if (MODE == 1) {
        bf16x4 hb;
        hb.x = (bf16_t)h.x; hb.y = (bf16_t)h.y; hb.z = (bf16_t)h.z; hb.w = (bf16_t)h.w;
        ((bf16x4*)out0v)[i] = hb;
        bf16x4 sv = ((const bf16x4*)s)[i];
        bf16x4 tb;
        tb.x = (bf16_t)(h.x + (float)sv.x); tb.y = (bf16_t)(h.y + (float)sv.y);
        tb.z = (bf16_t)(h.z + (float)sv.z); tb.w = (bf16_t)(h.w + (float)sv.w);
        ((bf16x4*)out1v)[i] = tb;
    } else if (MODE == 2) {
        bf16x4 hv = ((const bf16x4*)h1in)[i];
        bf16x4 sv = ((const bf16x4*)s)[i];
        bf16x4 tb;
        tb.x = (bf16_t)((float)hv.x + h.x + (float)sv.x);
        tb.y = (bf16_t)((float)hv.y + h.y + (float)sv.y);
        tb.z = (bf16_t)((float)hv.z + h.z + (float)sv.z);
        tb.w = (bf16_t)((float)hv.w + h.w + (float)sv.w);
        ((bf16x4*)out0v)[i] = tb;
    } else {
        ((float4*)out0v)[i] = h;
    }
}

// ------------------------------------------------------------------ launch
extern "C" void kernel_launch(void* const* d_in, const int* in_sizes, int n_in,
                              void* d_out, int out_size, void* d_ws, size_t ws_size,
                              hipStream_t stream) {
    const float* x    = (const float*)d_in[0];
    const int*   esrc = (const int*)d_in[1];
    const int*   edst = (const int*)d_in[2];
    const float* Wl1  = (const float*)d_in[3];
    const float* Wr1  = (const float*)d_in[4];
    const float* b1   = (const float*)d_in[5];
    const float* Wl2  = (const float*)d_in[6];
    const float* Wr2  = (const float*)d_in[7];
    const float* b2   = (const float*)d_in[8];
    const float* Wl3  = (const float*)d_in[9];
    const float* Wr3  = (const float*)d_in[10];
    const float* b3   = (const float*)d_in[11];
    const float* Ws1  = (const float*)d_in[12];
    const float* Ws2  = (const float*)d_in[13];
    const float* lnw1 = (const float*)d_in[14];
    const float* lnb1 = (const float*)d_in[15];
    const float* lnw2 = (const float*)d_in[16];
    const float* lnb2 = (const float*)d_in[17];
    const float* lnw3 = (const float*)d_in[18];
    const float* lnb3 = (const float*)d_in[19];
    const float* a1   = (const float*)d_in[20];
    const float* a2   = (const float*)d_in[21];
    const float* a3   = (const float*)d_in[22];

    const int N = in_sizes[0] / D_IN;
    const int E = in_sizes[1];
    const int NB = (N + 255) >> BSH;

    char* ws = (char*)d_ws;
    size_t off = 0;
    auto alloc = [&](size_t bytes) -> void* {
        void* p = ws + off;
        off += (bytes + 255) & ~(size_t)255;
        return p;
    };
    bf16_t* xb   = (bf16_t*)alloc((size_t)N * 64 * 2);
    bf16_t* mean = (bf16_t*)alloc((size_t)N * 128 * 2);
    bf16_t* PRE  = (bf16_t*)alloc((size_t)N * 128 * 2);
    bf16_t* C1   = (bf16_t*)alloc((size_t)N * 128 * 2);
    bf16_t* C2   = (bf16_t*)alloc((size_t)N * 128 * 2);
    bf16_t* h1b  = (bf16_t*)alloc((size_t)N * 128 * 2);
    bf16_t* TB   = (bf16_t*)alloc((size_t)N * 128 * 2);
    bf16_t* WT   = (bf16_t*)alloc((size_t)(4 * 128 * 64 + 4 * 128 * 128) * 2);
    int* cnt  = (int*)alloc((size_t)N * 4);
    int* rp   = (int*)alloc((size_t)(N + 1) * 4);
    int* col  = (int*)alloc((size_t)E * 4);
    int* part = (int*)alloc(512);
    int* bcnt = (int*)alloc((size_t)MAXB * 16 * 4);
    int* boff = (int*)alloc((size_t)(MAXB + 1) * 4);
    int* bpos = (int*)alloc((size_t)MAXB * 16 * 4);
    unsigned* pool = (unsigned*)alloc((size_t)E * 4);
    double* lnacc = (double*)alloc(6 * 8);
    const int tiles = (N + 31) / 32;
    float2* partials = (float2*)alloc((size_t)tiles * 8);

    bf16_t* Wl1T = WT;
    bf16_t* Wr1T = Wl1T + 128 * 64;
    bf16_t* Ws1T = Wr1T + 128 * 64;
    bf16_t* Ws2T = Ws1T + 128 * 64;
    bf16_t* Wl2T = Ws2T + 128 * 64;
    bf16_t* Wr2T = Wl2T + 128 * 128;
    bf16_t* Wl3T = Wr2T + 128 * 128;
    bf16_t* Wr3T = Wl3T + 128 * 128;

    hipMemsetAsync(bcnt, 0, (size_t)MAXB * 16 * 4, stream);

    // --- bucketed CSR build
    const int NBS_n = (N + 1023) / 1024;
    bucket_hist_k<<<256, 256, 0, stream>>>(edst, bcnt, E, NB);
    bscan_k<<<1, MAXB, 0, stream>>>(bcnt, boff, bpos, NB, E);
    scatter_k<<<256, 256, 0, stream>>>(esrc, edst, bpos, pool, E, NB);
    nhist_k<<<NB, 256, 0, stream>>>(pool, boff, cnt, N);
    scan_partial_k<<<NBS_n, 256, 0, stream>>>(cnt, part, N);
    scan_root_k<<<1, 256, 0, stream>>>(part, NBS_n);
    scan_final_k<<<NBS_n, 256, 0, stream>>>(cnt, part, rp, N);
    cfill_k<<<NB, 256, 0, stream>>>(pool, boff, rp, col, N);

    // --- weight/feature conversion
    ConvArgs ca;
    ca.d[0] = {Wl1, Wl1T, 50, 64};
    ca.d[1] = {Wr1, Wr1T, 50, 64};
    ca.d[2] = {Ws1, Ws1T, 50, 64};
    ca.d[3] = {Ws2, Ws2T, 50, 64};
    ca.d[4] = {Wl2, Wl2T, 128, 128};
    ca.d[5] = {Wr2, Wr2T, 128, 128};
    ca.d[6] = {Wl3, Wl3T, 128, 128};
    ca.d[7] = {Wr3, Wr3T, 128, 128};
    conv_w_k<<<dim3(64, 8), 256, 0, stream>>>(ca);
    conv_x_k<<<(N * 64 + 255) / 256, 256, 0, stream>>>(x, xb, N);

    const int aggBlocks = ((N * 64) + 255) / 256;
    const int gemmBlocks = (tiles + 3) / 4;
    const int lnBlocks = (N * 128 / 4 + 255) / 256;
    const int total = N * 128;

    // ---- layer 1 (triple-fused GEMM: PRE, C1=x@Ws1, C2=x@Ws2)
    agg_bf64_k<<<aggBlocks, 256, 0, stream>>>(xb, rp, col, mean, N);
    mfma_gemm3_k<<<gemmBlocks, 256, 0, stream>>>(
        mean, xb, Wl1T, Wr1T, Ws1T, Ws2T, b1, PRE, C1, C2, partials, N);
    reduce_partials_k<<<1, 256, 0, stream>>>(partials, tiles, lnacc + 0);
    ln_prelu_k<1><<<lnBlocks, 256, 0, stream>>>(
        PRE, nullptr, C1, lnw1, lnb1, a1, lnacc + 0, h1b, TB, total);

    // ---- layer 2
    agg_bf128_k<<<aggBlocks, 256, 0, stream>>>(TB, rp, col, mean, N);
    mfma_gemm_k<128, true, true><<<gemmBlocks, 256, 0, stream>>>(
        mean, TB, Wl2T, Wr2T, b2, PRE, partials, N);
    reduce_partials_k<<<1, 256, 0, stream>>>(partials, tiles, lnacc + 2);
    ln_prelu_k<2><<<lnBlocks, 256, 0, stream>>>(
        PRE, h1b, C2, lnw2, lnb2, a2, lnacc + 2, TB, nullptr, total);

    // ---- layer 3
    agg_bf128_k<<<aggBlocks, 256, 0, stream>>>(TB, rp, col, mean, N);
    mfma_gemm_k<128, true, true><<<gemmBlocks, 256, 0, stream>>>(
        mean, TB, Wl3T, Wr3T, b3, PRE, partials, N);
    reduce_partials_k<<<1, 256, 0, stream>>>(partials, tiles, lnacc + 4);
    ln_prelu_k<3><<<lnBlocks, 256, 0, stream>>>(
        PRE, nullptr, nullptr, lnw3, lnb3, a3, lnacc + 4, d_out, nullptr, total);
}